// Round 19
// baseline (303.807 us; speedup 1.0000x reference)
//
#include <hip/hip_runtime.h>
#include <hip/hip_bf16.h>

#define NODES 16384
#define FEAT 512
typedef __hip_bfloat16 bf16;
typedef __hip_bfloat162 bf162;
typedef short short8v __attribute__((ext_vector_type(8)));
typedef float f32x4 __attribute__((ext_vector_type(4)));

static __device__ __forceinline__ float b2f(short s){
  return __uint_as_float(((unsigned)(unsigned short)s) << 16);
}
static __device__ __forceinline__ void split_store(bf16* h, bf16* l, size_t i, float v){
  bf16 hi = __float2bfloat16(v);
  h[i] = hi; l[i] = __float2bfloat16(v - __bfloat162float(hi));
}

// ---------------- diagnostic sentinel ----------------
__global__ void sentinel_kernel(float* __restrict__ out, int n, float v){
  int i = blockIdx.x*blockDim.x + threadIdx.x;
  if (i < n) out[i] = v;
}

// ---------------- CSR build ----------------
__global__ void zero_kernel(int* __restrict__ p, int n){
  int i = blockIdx.x*blockDim.x + threadIdx.x;
  if (i < n) p[i] = 0;
}
__global__ void count_kernel(const int* __restrict__ ei, int* __restrict__ counts, int E){
  int i = blockIdx.x*blockDim.x + threadIdx.x;
  if (i < 2*E){
    int dst = (i < E) ? ei[E+i] : ei[i-E];
    atomicAdd(&counts[dst], 1);
  }
}
__global__ __launch_bounds__(1024) void scan_kernel(const int* __restrict__ counts,
                                                    int* __restrict__ offs, int* __restrict__ cursor){
  __shared__ int sh[1024];
  const int t = threadIdx.x;
  int loc[16]; int s = 0;
#pragma unroll
  for (int i=0;i<16;i++){ loc[i] = counts[t*16+i]; s += loc[i]; }
  sh[t] = s; __syncthreads();
  for (int d=1; d<1024; d<<=1){
    int v = (t>=d) ? sh[t-d] : 0;
    __syncthreads(); sh[t] += v; __syncthreads();
  }
  int run = (t==0) ? 0 : sh[t-1];
#pragma unroll
  for (int i=0;i<16;i++){ offs[t*16+i] = run; cursor[t*16+i] = run; run += loc[i]; }
  if (t==1023) offs[NODES] = run;
}
__global__ void fill_kernel(const int* __restrict__ ei, int* __restrict__ cursor,
                            unsigned short* __restrict__ csr, int E){
  int i = blockIdx.x*blockDim.x + threadIdx.x;
  if (i < 2*E){
    int src = ei[i];
    int dst = (i < E) ? ei[E+i] : ei[i-E];
    int pos = atomicAdd(&cursor[dst], 1);
    csr[pos] = (unsigned short)src;
  }
}

// ---------------- prep: x cast + LDS-tiled transpose-cast of all weights ----------------
struct PrepArgs {
  const float *x,*W1,*W2,*wv,*wo,*f1,*f2;
  bf16 *xh,*w1h,*w2h,*wvh,*wvl,*woh,*wol,*f1h,*f1l,*f2h,*f2l;
};
// blocks 0..511: x cast. blocks 512..631: 64x64 transpose tiles (coalesced both sides).
__global__ __launch_bounds__(256) void prep_kernel(PrepArgs P){
  const int b = blockIdx.x;
  const int t = threadIdx.x;
  if (b < 512){
    const size_t base = (size_t)b*4096;
#pragma unroll
    for (int k=0;k<16;k++){
      const size_t i = base + t + 256*k;
      P.xh[i] = __float2bfloat16(P.x[i]);
    }
    return;
  }
  __shared__ float tile[64][65];
  const float* src; bf16 *dh; bf16 *dl; int R, C, ti;
  int bb = b - 512;
  if (bb < 16){ src=P.W1; dh=P.w1h; dl=nullptr; R=128; C=512; ti=bb; }
  else if ((bb-=16) < 64){ src=P.W2; dh=P.w2h; dl=nullptr; R=512; C=512; ti=bb; }
  else if ((bb-=64) < 4){ src=P.wv; dh=P.wvh; dl=P.wvl; R=128; C=128; ti=bb; }
  else if ((bb-=4) < 4){ src=P.wo; dh=P.woh; dl=P.wol; R=128; C=128; ti=bb; }
  else if ((bb-=4) < 16){ src=P.f1; dh=P.f1h; dl=P.f1l; R=128; C=512; ti=bb; }
  else { bb-=16; src=P.f2; dh=P.f2h; dl=P.f2l; R=512; C=128; ti=bb; }
  const int ctiles = C/64;
  const int r0 = (ti/ctiles)*64, c0 = (ti%ctiles)*64;
  const int r = t >> 6, c = t & 63;
#pragma unroll
  for (int i=0;i<16;i++)
    tile[r + 4*i][c] = src[(size_t)(r0 + r + 4*i)*C + c0 + c];
  __syncthreads();
#pragma unroll
  for (int i=0;i<16;i++){
    const int oc   = c0 + r + 4*i;   // output row (original column)
    const int orow = r0 + c;         // output col (original row)
    const float v = tile[c][r + 4*i];
    const size_t oi = (size_t)oc*R + orow;
    if (dl){ split_store(dh, dl, oi, v); } else { dh[oi] = __float2bfloat16(v); }
  }
}

static __device__ __forceinline__ short8v ld8(const bf16* p){
  return *(const short8v*)(const void*)(p);
}

// ---------------- LDS-staged MFMA GEMM (m93-style): 128x128 block tile, 4 waves ----------------
template<int K>
__global__ __launch_bounds__(256) void lgemm(
    const bf16* __restrict__ A, const bf16* __restrict__ B,
    bf16* __restrict__ C, int N){
  __shared__ bf16 As[128*40];
  __shared__ bf16 Bs[128*40];
  const int tid = threadIdx.x;
  const int l = tid & 63, w = tid >> 6;
  const int lg = l >> 4, lr = l & 15;
  const int wr = w >> 1, wc = w & 1;
  const int r0 = blockIdx.x*128;
  const int c0 = blockIdx.y*128;
  const int srow = tid >> 1;
  const int spos = (tid & 1) * 16;
  f32x4 acc[4][4] = {};
  const int ardA[4] = { (wr*64 +  0 + lr)*40 + lg*8, (wr*64 + 16 + lr)*40 + lg*8,
                        (wr*64 + 32 + lr)*40 + lg*8, (wr*64 + 48 + lr)*40 + lg*8 };
  const int brdB[4] = { (wc*64 +  0 + lr)*40 + lg*8, (wc*64 + 16 + lr)*40 + lg*8,
                        (wc*64 + 32 + lr)*40 + lg*8, (wc*64 + 48 + lr)*40 + lg*8 };
  const size_t agbase = (size_t)(r0 + srow)*K + spos;
  const size_t bgbase = (size_t)(c0 + srow)*K + spos;
  const int sl = srow*40 + spos;
#pragma unroll
  for (int k0 = 0; k0 < K; k0 += 32){
    *(short8v*)&As[sl]     = ld8(A + agbase + k0);
    *(short8v*)&As[sl + 8] = ld8(A + agbase + k0 + 8);
    *(short8v*)&Bs[sl]     = ld8(B + bgbase + k0);
    *(short8v*)&Bs[sl + 8] = ld8(B + bgbase + k0 + 8);
    __syncthreads();
    short8v af[4], bfr[4];
#pragma unroll
    for (int f=0; f<4; f++){
      af[f]  = *(const short8v*)&As[ardA[f]];
      bfr[f] = *(const short8v*)&Bs[brdB[f]];
    }
#pragma unroll
    for (int fm=0; fm<4; fm++)
#pragma unroll
      for (int fn=0; fn<4; fn++)
        acc[fm][fn] = __builtin_amdgcn_mfma_f32_16x16x32_bf16(af[fm], bfr[fn], acc[fm][fn], 0,0,0);
    __syncthreads();
  }
#pragma unroll
  for (int fm=0; fm<4; fm++){
#pragma unroll
    for (int fn=0; fn<4; fn++){
      const int col = c0 + wc*64 + fn*16 + lr;
#pragma unroll
      for (int r=0; r<4; r++){
        const int row = r0 + wr*64 + fm*16 + lg*4 + r;
        C[(size_t)row*N + col] = __float2bfloat16(acc[fm][fn][r]);
      }
    }
  }
}

// ---------------- direct-reg MFMA GEMM (tail: split-precision small GEMMs) ----------------
template<int K, int SA, int SB, int ACT, int OMODE, int WPB>
__global__ __launch_bounds__(256) void mgemm(
    const bf16* __restrict__ Ah, const bf16* __restrict__ Al,
    const bf16* __restrict__ Bh, const bf16* __restrict__ Bl,
    const float* __restrict__ bias,
    float* __restrict__ Cf, bf16* __restrict__ Ch, bf16* __restrict__ Cl, int N){
  const int l = threadIdx.x & 63, w = threadIdx.x >> 6;
  const int lg = l >> 4, lr = l & 15;
  const int r0 = (blockIdx.x*WPB + w)*64;
  const int c0 = blockIdx.y*64;
  f32x4 acc[4][4] = {};
  int abase[4], bbase[4];
#pragma unroll
  for (int f=0; f<4; f++){
    abase[f] = (r0 + f*16 + lr)*K + lg*8;
    bbase[f] = (c0 + f*16 + lr)*K + lg*8;
  }
#pragma unroll
  for (int k0 = 0; k0 < K; k0 += 32){
    short8v ah[4], alo[4], bh[4], blo[4];
#pragma unroll
    for (int f=0; f<4; f++){
      ah[f] = ld8(Ah + abase[f] + k0);
      if (SA) alo[f] = ld8(Al + abase[f] + k0);
      bh[f] = ld8(Bh + bbase[f] + k0);
      if (SB) blo[f] = ld8(Bl + bbase[f] + k0);
    }
#pragma unroll
    for (int fm=0; fm<4; fm++)
#pragma unroll
      for (int fn=0; fn<4; fn++){
        acc[fm][fn] = __builtin_amdgcn_mfma_f32_16x16x32_bf16(ah[fm], bh[fn], acc[fm][fn], 0,0,0);
        if (SB) acc[fm][fn] = __builtin_amdgcn_mfma_f32_16x16x32_bf16(ah[fm], blo[fn], acc[fm][fn], 0,0,0);
        if (SA) acc[fm][fn] = __builtin_amdgcn_mfma_f32_16x16x32_bf16(alo[fm], bh[fn], acc[fm][fn], 0,0,0);
      }
  }
#pragma unroll
  for (int fm=0; fm<4; fm++){
#pragma unroll
    for (int fn=0; fn<4; fn++){
      const int col = c0 + fn*16 + lr;
      const float bv = bias ? bias[col] : 0.f;
#pragma unroll
      for (int r=0; r<4; r++){
        const int row = r0 + fm*16 + lg*4 + r;
        float v = acc[fm][fn][r] + bv;
        if (ACT==1) v = fmaxf(v, 0.f);
        const size_t idx = (size_t)row*N + col;
        if (OMODE==0) Cf[idx] = v;
        else if (OMODE==1) Ch[idx] = __float2bfloat16(v);
        else split_store(Ch, Cl, idx, v);
      }
    }
  }
}

// ---------------- attention coefficients ----------------
__global__ __launch_bounds__(256) void alsald_kernel(const bf16* __restrict__ h,
    const float* __restrict__ a_s, const float* __restrict__ a_d,
    float* __restrict__ als, float* __restrict__ ald){
  int n = blockIdx.x;
  int w = threadIdx.x >> 6, lane = threadIdx.x & 63;
  int c = w*128 + lane*2;
  bf162 hv = *(const bf162*)&h[(size_t)n*FEAT + c];
  float hx = __bfloat162float(hv.x), hy = __bfloat162float(hv.y);
  float2 as2 = *(const float2*)&a_s[c];
  float2 ad2 = *(const float2*)&a_d[c];
  float s = hx*as2.x + hy*as2.y;
  float d = hx*ad2.x + hy*ad2.y;
#pragma unroll
  for (int o=32;o>0;o>>=1){ s += __shfl_xor(s,o); d += __shfl_xor(d,o); }
  if (lane == 0){ als[n*4+w] = s; ald[n*4+w] = d; }
}

// ---------------- fused GAT aggregation: 2 waves per node (even/odd pages) ----------------
// each wave: phase1 on its 3 pages -> LDS (m,den) exchange -> identical C in both waves;
// phase2 on its pages; acc merged via LDS; half0 does epilogue.
template<bool CONCAT>
__global__ __launch_bounds__(256) void gat_fused_kernel(const bf16* __restrict__ hfeat,
    const float* __restrict__ als, const float* __restrict__ ald,
    const int* __restrict__ offs, const unsigned short* __restrict__ csr,
    const float* __restrict__ bias, void* __restrict__ outv,
    bf16* __restrict__ qh, bf16* __restrict__ ql){
  __shared__ float mdbuf[2][2][4][2];   // [pair][half][head][m,den]
  __shared__ float mbuf[2][64][8];      // acc merge
  const int w = threadIdx.x >> 6, l = threadIdx.x & 63, g = l >> 4, s16 = l & 15;
  const int half = w & 1, pair = w >> 1;
  const int nb = blockIdx.x;                        // NODES/2 blocks
  const int n = (nb & 7)*2048 + (nb >> 3)*2 + pair; // cluster-contiguous, XCD-aligned
  const float adg = ald[(size_t)n*4 + g];
  const int beg = offs[n];
  const int cnt = offs[n+1] - beg + 1;              // + implicit self-loop (edge cnt-1)
  // ---- phase 1: own pages p = half + 2*i ----
  float ev[3]; int sv[3];
#pragma unroll
  for (int i=0;i<3;i++){
    const int p = half + 2*i;
    const int idx = s16 + p*16;
    int src = n;
    float e = -1e30f;
    if (idx < cnt){
      if (idx < cnt-1) src = (int)csr[beg+idx];
      float t = als[(size_t)src*4+g] + adg;
      e = fmaxf(t, 0.2f*t);                         // leaky_relu 0.2
    }
    ev[i] = e; sv[i] = src;
  }
  float m = fmaxf(fmaxf(ev[0], ev[1]), ev[2]);
  float den = 0.f;
#pragma unroll
  for (int i=0;i<3;i++) den += (ev[i] > -1e29f) ? __expf(ev[i]-m) : 0.f;
#pragma unroll
  for (int mask=1; mask<16; mask<<=1){
    float mo = __shfl_xor(m, mask);
    float dd = __shfl_xor(den, mask);
    float nm = fmaxf(m, mo);
    den = den*__expf(m-nm) + dd*__expf(mo-nm);
    m = nm;
  }
  if (s16 == 0){ mdbuf[pair][half][g][0] = m; mdbuf[pair][half][g][1] = den; }
  __syncthreads();
  {
    const float mo = mdbuf[pair][half^1][g][0];
    const float dd = mdbuf[pair][half^1][g][1];
    const float nm = fmaxf(m, mo);
    den = den*__expf(m-nm) + dd*__expf(mo-nm);      // commutative merge -> identical C both waves
    m = nm;
  }
  const float C = __expf(-m)/(den + 1e-16f);
  int pk[3];
#pragma unroll
  for (int i=0;i<3;i++){
    float a = (ev[i] > -1e29f) ? __expf(ev[i])*C : 0.f;
    bf16 ab = __float2bfloat16(a);
    pk[i] = ((int)*(unsigned short*)&ab << 16) | (sv[i] & 0xFFFF);
  }
  // ---- phase 2: own pages; packed (alpha,src) via ONE shfl; 2-deep pipeline ----
  float acc[8] = {0,0,0,0,0,0,0,0};
  const int fb = l*8;
  const bf16* hp = hfeat + fb;
#pragma unroll
  for (int i=0;i<3;i++){
    const int pbase = (half + 2*i)*16;
    if (pbase < cnt){
      const int lim = (cnt - pbase < 16) ? (cnt - pbase) : 16;
      int u_c = __shfl(pk[i], (l & 48));
      short8v hv_c = *(const short8v*)(const void*)(hp + (size_t)(u_c & 0xFFFF)*FEAT);
      for (int j=1; j<lim; ++j){
        const int u_n = __shfl(pk[i], (l & 48) | j);
        const short8v hv_n = *(const short8v*)(const void*)(hp + (size_t)(u_n & 0xFFFF)*FEAT);
        const float a_c = __uint_as_float((unsigned)u_c & 0xFFFF0000u);
#pragma unroll
        for (int k=0;k<8;k++) acc[k] += a_c * b2f(hv_c[k]);
        u_c = u_n; hv_c = hv_n;
      }
      const float a_c = __uint_as_float((unsigned)u_c & 0xFFFF0000u);
#pragma unroll
      for (int k=0;k<8;k++) acc[k] += a_c * b2f(hv_c[k]);
    }
  }
  if (half == 0){
    for (int i = 96; i < cnt; ++i){                 // correctness guard, cnt>96
      const int src = (i < cnt-1) ? (int)csr[beg+i] : n;
      float t = als[(size_t)src*4+g] + adg;
      t = fmaxf(t, 0.2f*t);
      const float a = __expf(t)*C;
      const short8v hv = *(const short8v*)(const void*)&hfeat[(size_t)src*FEAT + fb];
#pragma unroll
      for (int k=0;k<8;k++) acc[k] += a * b2f(hv[k]);
    }
  }
  if (half == 1){
#pragma unroll
    for (int k=0;k<8;k++) mbuf[pair][l][k] = acc[k];
  }
  __syncthreads();
  if (half == 1) return;
#pragma unroll
  for (int k=0;k<8;k++) acc[k] += mbuf[pair][l][k];
  if (CONCAT){
    short8v ov;
#pragma unroll
    for (int j=0;j<8;j++){
      float v = acc[j] + bias[fb+j];
      v = v > 0.f ? v : expm1f(v);                  // fused ELU
      bf16 bv = __float2bfloat16(v);
      ov[j] = (short)*(unsigned short*)&bv;
    }
    *(short8v*)((char*)outv + ((size_t)n*FEAT + fb)*2) = ov;
  } else {
#pragma unroll
    for (int j=0;j<8;j++){
      acc[j] += __shfl_xor(acc[j], 16);
      acc[j] += __shfl_xor(acc[j], 32);
    }
    if (l < 16){
      float* op = (float*)outv + (size_t)n*128 + l*8;
#pragma unroll
      for (int j=0;j<8;j++){
        const int col = l*8 + j;
        float v = 0.25f*acc[j] + bias[col];
        float ex = __expf((float)(col & ~1) * (-9.210340371976184f/128.f));
        float pe = (col & 1) ? cosf(4.f*ex) : sinf(4.f*ex);
        float q = v + pe;
        op[j] = q;
        split_store(qh, ql, (size_t)n*128 + col, q);
      }
    }
  }
}

// ---------------- LayerNorm(a+b), optional bf16 split output ----------------
template<int SPLIT>
__global__ __launch_bounds__(256) void ln_kernel(const float* __restrict__ a, const float* __restrict__ b,
    const float* __restrict__ g, const float* __restrict__ bb, float* __restrict__ out,
    bf16* __restrict__ oh, bf16* __restrict__ ol){
  int row = blockIdx.x*4 + (threadIdx.x >> 6);
  int lane = threadIdx.x & 63;
  int c = lane*2;
  float2 va = *(const float2*)&a[(size_t)row*128 + c];
  float2 vb = *(const float2*)&b[(size_t)row*128 + c];
  float x0 = va.x+vb.x, x1 = va.y+vb.y;
  float s = x0+x1, q = x0*x0 + x1*x1;
#pragma unroll
  for (int o=32;o>0;o>>=1){ s += __shfl_xor(s,o); q += __shfl_xor(q,o); }
  float mu = s*(1.f/128.f);
  float var = q*(1.f/128.f) - mu*mu;
  float r = 1.f/sqrtf(var + 1e-5f);
  float y0 = (x0-mu)*r*g[c]   + bb[c];
  float y1 = (x1-mu)*r*g[c+1] + bb[c+1];
  size_t idx = (size_t)row*128 + c;
  out[idx] = y0; out[idx+1] = y1;
  if (SPLIT){ split_store(oh, ol, idx, y0); split_store(oh, ol, idx+1, y1); }
}

// ---------------- fused LayerNorm2 + classifier head ----------------
__global__ __launch_bounds__(256) void ln_final_kernel(const float* __restrict__ a, const float* __restrict__ b,
    const float* __restrict__ g, const float* __restrict__ bb,
    const float* __restrict__ wc, const float* __restrict__ bc,
    float* __restrict__ out){
  int row = blockIdx.x*4 + (threadIdx.x >> 6);
  int lane = threadIdx.x & 63;
  int c = lane*2;
  float2 va = *(const float2*)&a[(size_t)row*128 + c];
  float2 vb = *(const float2*)&b[(size_t)row*128 + c];
  float x0 = va.x+vb.x, x1 = va.y+vb.y;
  float s = x0+x1, q = x0*x0 + x1*x1;
#pragma unroll
  for (int o=32;o>0;o>>=1){ s += __shfl_xor(s,o); q += __shfl_xor(q,o); }
  float mu = s*(1.f/128.f);
  float var = q*(1.f/128.f) - mu*mu;
  float r = 1.f/sqrtf(var + 1e-5f);
  float y0 = (x0-mu)*r*g[c]   + bb[c];
  float y1 = (x1-mu)*r*g[c+1] + bb[c+1];
  float s0 = y0*wc[c*2]   + y1*wc[(c+1)*2];
  float s1 = y0*wc[c*2+1] + y1*wc[(c+1)*2+1];
#pragma unroll
  for (int o=32;o>0;o>>=1){ s0 += __shfl_xor(s0,o); s1 += __shfl_xor(s1,o); }
  if (lane == 0){
    out[row*2]   = s0 + bc[0];
    out[row*2+1] = s1 + bc[1];
  }
}

extern "C" void kernel_launch(void* const* d_in, const int* in_sizes, int n_in,
                              void* d_out, int out_size, void* d_ws, size_t ws_size,
                              hipStream_t stream){
  const float* x      = (const float*)d_in[0];
  const int*   ei     = (const int*)d_in[1];
  const float* W1     = (const float*)d_in[3];
  const float* a_src1 = (const float*)d_in[4];
  const float* a_dst1 = (const float*)d_in[5];
  const float* b1     = (const float*)d_in[6];
  const float* W2     = (const float*)d_in[7];
  const float* a_src2 = (const float*)d_in[8];
  const float* a_dst2 = (const float*)d_in[9];
  const float* b2     = (const float*)d_in[10];
  const float* wv     = (const float*)d_in[15];
  const float* bv     = (const float*)d_in[16];
  const float* wo     = (const float*)d_in[17];
  const float* bo     = (const float*)d_in[18];
  const float* ln_g   = (const float*)d_in[19];
  const float* ln_b   = (const float*)d_in[20];
  const float* f1     = (const float*)d_in[21];
  const float* fb1    = (const float*)d_in[22];
  const float* f2     = (const float*)d_in[23];
  const float* fb2    = (const float*)d_in[24];
  const float* wc     = (const float*)d_in[25];
  const float* bc     = (const float*)d_in[26];
  float* outp = (float*)d_out;

  const int E = in_sizes[1] / 2;
  const int n = NODES;
  const int tE = 2*E;
  const size_t MB = 1024*1024;

  const size_t NEED = 36*MB;
  if (ws_size < NEED){
    sentinel_kernel<<<(out_size+255)/256, 256, 0, stream>>>(outp, out_size,
        1000.0f + (float)(ws_size / MB));
    return;
  }

  // ---- arena [0,36) MB; liveness audited phase-by-phase ----
  char* base = (char*)d_ws;
  int* counts = (int*)(base + 0);            // [0,64K)   pre-gemm1 only
  int* cursor = (int*)(base + 65536);        // [64K,128K)
  bf16*  h1    = (bf16*)(base + 0);          // [0,16)   gemm1 out -> agg1
  bf16*  xh    = (bf16*)(base + 16*MB);      // [16,20)  prep -> gemm1
  bf16*  h     = (bf16*)(base + 16*MB);      // [16,32)  agg1 out (xh dead) -> gemm2
  bf16*  h2f   = (bf16*)(base + 0);          // [0,16)   gemm2 out (h1 dead) -> agg2
  float* h2q   = (float*)(base + 16*MB);     // [16,24)  agg2 out f32 (h dead) -> ln1
  bf16*  qh    = (bf16*)(base + 24*MB);      // [24,28)  agg2 epilogue -> wv
  bf16*  ql    = (bf16*)(base + 28*MB);      // [28,32)
  bf16*  vh    = (bf16*)(base + 0);          // [0,4)    (h2f dead after agg2)
  bf16*  vl    = (bf16*)(base + 4*MB);       // [4,8)
  float* aobuf = (float*)(base + 8*MB);      // [8,16)
  float* y1    = (float*)(base + 24*MB);     // [24,32)  ln1 out (qh/ql dead after wv)
  bf16*  y1h   = (bf16*)(base + 0);          // [0,4)    (vh/vl dead after wo)
  bf16*  y1l   = (bf16*)(base + 4*MB);       // [4,8)
  bf16*  hidden= (bf16*)(base + 8*MB);       // [8,24)   16MB (aobuf,h2q dead after ln1)
  float* ffn2f = (float*)(base + 0);         // [0,8)    (y1h/l dead after ffn1)
  // S region [32,36): ~3.0 MB
  char* u = base + 32*MB;
  bf16* w1h = (bf16*)u; u += 131072;
  bf16* w2h = (bf16*)u; u += 524288;
  bf16* wvh = (bf16*)u; u += 32768;   bf16* wvl = (bf16*)u; u += 32768;
  bf16* woh = (bf16*)u; u += 32768;   bf16* wol = (bf16*)u; u += 32768;
  bf16* f1h = (bf16*)u; u += 131072;  bf16* f1l = (bf16*)u; u += 131072;
  bf16* f2h = (bf16*)u; u += 131072;  bf16* f2l = (bf16*)u; u += 131072;
  float* als  = (float*)u; u += (size_t)n*4*4;
  float* ald  = (float*)u; u += (size_t)n*4*4;
  int* offs   = (int*)u;   u += (size_t)(n+1)*4 + 252;
  unsigned short* csr = (unsigned short*)u; u += (size_t)tE*2;

  // ---- prep + CSR ----
  PrepArgs P = { x,W1,W2,wv,wo,f1,f2, xh,w1h,w2h,wvh,wvl,woh,wol,f1h,f1l,f2h,f2l };
  prep_kernel<<<632, 256, 0, stream>>>(P);
  zero_kernel<<<(n+255)/256, 256, 0, stream>>>(counts, n);
  count_kernel<<<(tE+255)/256, 256, 0, stream>>>(ei, counts, E);
  scan_kernel<<<1, 1024, 0, stream>>>(counts, offs, cursor);
  fill_kernel<<<(tE+255)/256, 256, 0, stream>>>(ei, cursor, csr, E);

  // ---- GAT layer 1 ----
  lgemm<128><<<dim3(128,4), 256, 0, stream>>>(xh, w1h, h1, 512);
  alsald_kernel<<<n, 256, 0, stream>>>(h1, a_src1, a_dst1, als, ald);
  gat_fused_kernel<true><<<n/2, 256, 0, stream>>>(h1, als, ald, offs, csr, b1, h, nullptr, nullptr);

  // ---- GAT layer 2 ----
  lgemm<512><<<dim3(128,4), 256, 0, stream>>>(h, w2h, h2f, 512);
  alsald_kernel<<<n, 256, 0, stream>>>(h2f, a_src2, a_dst2, als, ald);
  gat_fused_kernel<false><<<n/2, 256, 0, stream>>>(h2f, als, ald, offs, csr, b2, h2q, qh, ql);

  // ---- temporal attention (collapsed to V at l=L-1) + head: split-precision tail ----
  mgemm<128,1,1,0,2,2><<<dim3(128,2), 128, 0, stream>>>(qh, ql, wvh, wvl, bv, nullptr, vh, vl, 128);
  mgemm<128,1,1,0,0,2><<<dim3(128,2), 128, 0, stream>>>(vh, vl, woh, wol, bo, aobuf, nullptr, nullptr, 128);
  ln_kernel<1><<<n/4, 256, 0, stream>>>(h2q, aobuf, ln_g, ln_b, y1, y1h, y1l);
  mgemm<128,1,1,1,1,4><<<dim3(64,8), 256, 0, stream>>>(y1h, y1l, f1h, f1l, fb1, nullptr, hidden, nullptr, 512);
  mgemm<512,0,1,0,0,2><<<dim3(128,2), 128, 0, stream>>>(hidden, nullptr, f2h, f2l, fb2, ffn2f, nullptr, nullptr, 128);
  ln_final_kernel<<<n/4, 256, 0, stream>>>(y1, ffn2f, ln_g, ln_b, wc, bc, outp);
}

// Round 20
// 278.733 us; speedup vs baseline: 1.0900x; 1.0900x over previous
//
#include <hip/hip_runtime.h>
#include <hip/hip_bf16.h>

#define NODES 16384
#define FEAT 512
typedef __hip_bfloat16 bf16;
typedef __hip_bfloat162 bf162;
typedef short short8v __attribute__((ext_vector_type(8)));
typedef float f32x4 __attribute__((ext_vector_type(4)));

static __device__ __forceinline__ float b2f(short s){
  return __uint_as_float(((unsigned)(unsigned short)s) << 16);
}
static __device__ __forceinline__ void split_store(bf16* h, bf16* l, size_t i, float v){
  bf16 hi = __float2bfloat16(v);
  h[i] = hi; l[i] = __float2bfloat16(v - __bfloat162float(hi));
}

// ---------------- diagnostic sentinel ----------------
__global__ void sentinel_kernel(float* __restrict__ out, int n, float v){
  int i = blockIdx.x*blockDim.x + threadIdx.x;
  if (i < n) out[i] = v;
}

// ---------------- CSR build ----------------
__global__ void zero_kernel(int* __restrict__ p, int n){
  int i = blockIdx.x*blockDim.x + threadIdx.x;
  if (i < n) p[i] = 0;
}
__global__ void count_kernel(const int* __restrict__ ei, int* __restrict__ counts, int E){
  int i = blockIdx.x*blockDim.x + threadIdx.x;
  if (i < 2*E){
    int dst = (i < E) ? ei[E+i] : ei[i-E];
    atomicAdd(&counts[dst], 1);
  }
}
__global__ __launch_bounds__(1024) void scan_kernel(const int* __restrict__ counts,
                                                    int* __restrict__ offs, int* __restrict__ cursor){
  __shared__ int sh[1024];
  const int t = threadIdx.x;
  int loc[16]; int s = 0;
#pragma unroll
  for (int i=0;i<16;i++){ loc[i] = counts[t*16+i]; s += loc[i]; }
  sh[t] = s; __syncthreads();
  for (int d=1; d<1024; d<<=1){
    int v = (t>=d) ? sh[t-d] : 0;
    __syncthreads(); sh[t] += v; __syncthreads();
  }
  int run = (t==0) ? 0 : sh[t-1];
#pragma unroll
  for (int i=0;i<16;i++){ offs[t*16+i] = run; cursor[t*16+i] = run; run += loc[i]; }
  if (t==1023) offs[NODES] = run;
}
__global__ void fill_kernel(const int* __restrict__ ei, int* __restrict__ cursor,
                            unsigned short* __restrict__ csr, int E){
  int i = blockIdx.x*blockDim.x + threadIdx.x;
  if (i < 2*E){
    int src = ei[i];
    int dst = (i < E) ? ei[E+i] : ei[i-E];
    int pos = atomicAdd(&cursor[dst], 1);
    csr[pos] = (unsigned short)src;
  }
}

// ---------------- prep: x cast + LDS-tiled transpose-cast of all weights ----------------
struct PrepArgs {
  const float *x,*W1,*W2,*wv,*wo,*f1,*f2;
  bf16 *xh,*w1h,*w2h,*wvh,*wvl,*woh,*wol,*f1h,*f1l,*f2h,*f2l;
};
__global__ __launch_bounds__(256) void prep_kernel(PrepArgs P){
  const int b = blockIdx.x;
  const int t = threadIdx.x;
  if (b < 512){
    const size_t base = (size_t)b*4096;
#pragma unroll
    for (int k=0;k<16;k++){
      const size_t i = base + t + 256*k;
      P.xh[i] = __float2bfloat16(P.x[i]);
    }
    return;
  }
  __shared__ float tile[64][65];
  const float* src; bf16 *dh; bf16 *dl; int R, C, ti;
  int bb = b - 512;
  if (bb < 16){ src=P.W1; dh=P.w1h; dl=nullptr; R=128; C=512; ti=bb; }
  else if ((bb-=16) < 64){ src=P.W2; dh=P.w2h; dl=nullptr; R=512; C=512; ti=bb; }
  else if ((bb-=64) < 4){ src=P.wv; dh=P.wvh; dl=P.wvl; R=128; C=128; ti=bb; }
  else if ((bb-=4) < 4){ src=P.wo; dh=P.woh; dl=P.wol; R=128; C=128; ti=bb; }
  else if ((bb-=4) < 16){ src=P.f1; dh=P.f1h; dl=P.f1l; R=128; C=512; ti=bb; }
  else { bb-=16; src=P.f2; dh=P.f2h; dl=P.f2l; R=512; C=128; ti=bb; }
  const int ctiles = C/64;
  const int r0 = (ti/ctiles)*64, c0 = (ti%ctiles)*64;
  const int r = t >> 6, c = t & 63;
#pragma unroll
  for (int i=0;i<16;i++)
    tile[r + 4*i][c] = src[(size_t)(r0 + r + 4*i)*C + c0 + c];
  __syncthreads();
#pragma unroll
  for (int i=0;i<16;i++){
    const int oc   = c0 + r + 4*i;
    const int orow = r0 + c;
    const float v = tile[c][r + 4*i];
    const size_t oi = (size_t)oc*R + orow;
    if (dl){ split_store(dh, dl, oi, v); } else { dh[oi] = __float2bfloat16(v); }
  }
}

static __device__ __forceinline__ short8v ld8(const bf16* p){
  return *(const short8v*)(const void*)(p);
}

// ---------------- LDS-staged MFMA GEMM: 128x128 block tile, 4 waves, split-capable ----------------
// A row-major [M][K] (+lo if SA); B transposed [N][K] (+lo if SB). Per-output-element MFMA
// order: k ascending, bh -> blo -> alo (identical to prior mgemm -> bit-identical results).
template<int K, int SA, int SB, int ACT, int OMODE>
__global__ __launch_bounds__(256) void lgemm(
    const bf16* __restrict__ A, const bf16* __restrict__ Al,
    const bf16* __restrict__ B, const bf16* __restrict__ Bl,
    const float* __restrict__ bias,
    float* __restrict__ Cf, bf16* __restrict__ Ch, bf16* __restrict__ Cl, int N){
  __shared__ bf16 As[128*40];
  __shared__ bf16 Bs[128*40];
  __shared__ bf16 Asl[SA ? 128*40 : 1];
  __shared__ bf16 Bsl[SB ? 128*40 : 1];
  const int tid = threadIdx.x;
  const int l = tid & 63, w = tid >> 6;
  const int lg = l >> 4, lr = l & 15;
  const int wr = w >> 1, wc = w & 1;
  const int r0 = blockIdx.x*128;
  const int c0 = blockIdx.y*128;
  const int srow = tid >> 1;
  const int spos = (tid & 1) * 16;
  f32x4 acc[4][4] = {};
  const int ard[4] = { (wr*64 +  0 + lr)*40 + lg*8, (wr*64 + 16 + lr)*40 + lg*8,
                       (wr*64 + 32 + lr)*40 + lg*8, (wr*64 + 48 + lr)*40 + lg*8 };
  const int brd[4] = { (wc*64 +  0 + lr)*40 + lg*8, (wc*64 + 16 + lr)*40 + lg*8,
                       (wc*64 + 32 + lr)*40 + lg*8, (wc*64 + 48 + lr)*40 + lg*8 };
  const size_t agbase = (size_t)(r0 + srow)*K + spos;
  const size_t bgbase = (size_t)(c0 + srow)*K + spos;
  const int sl = srow*40 + spos;
#pragma unroll
  for (int k0 = 0; k0 < K; k0 += 32){
    *(short8v*)&As[sl]     = ld8(A + agbase + k0);
    *(short8v*)&As[sl + 8] = ld8(A + agbase + k0 + 8);
    *(short8v*)&Bs[sl]     = ld8(B + bgbase + k0);
    *(short8v*)&Bs[sl + 8] = ld8(B + bgbase + k0 + 8);
    if (SA){
      *(short8v*)&Asl[sl]     = ld8(Al + agbase + k0);
      *(short8v*)&Asl[sl + 8] = ld8(Al + agbase + k0 + 8);
    }
    if (SB){
      *(short8v*)&Bsl[sl]     = ld8(Bl + bgbase + k0);
      *(short8v*)&Bsl[sl + 8] = ld8(Bl + bgbase + k0 + 8);
    }
    __syncthreads();
    short8v af[4], bfr[4], afl[4], bfl[4];
#pragma unroll
    for (int f=0; f<4; f++){
      af[f]  = *(const short8v*)&As[ard[f]];
      bfr[f] = *(const short8v*)&Bs[brd[f]];
      if (SA) afl[f] = *(const short8v*)&Asl[ard[f]];
      if (SB) bfl[f] = *(const short8v*)&Bsl[brd[f]];
    }
#pragma unroll
    for (int fm=0; fm<4; fm++)
#pragma unroll
      for (int fn=0; fn<4; fn++){
        acc[fm][fn] = __builtin_amdgcn_mfma_f32_16x16x32_bf16(af[fm], bfr[fn], acc[fm][fn], 0,0,0);
        if (SB) acc[fm][fn] = __builtin_amdgcn_mfma_f32_16x16x32_bf16(af[fm], bfl[fn], acc[fm][fn], 0,0,0);
        if (SA) acc[fm][fn] = __builtin_amdgcn_mfma_f32_16x16x32_bf16(afl[fm], bfr[fn], acc[fm][fn], 0,0,0);
      }
    __syncthreads();
  }
#pragma unroll
  for (int fm=0; fm<4; fm++){
#pragma unroll
    for (int fn=0; fn<4; fn++){
      const int col = c0 + wc*64 + fn*16 + lr;
      const float bv = bias ? bias[col] : 0.f;
#pragma unroll
      for (int r=0; r<4; r++){
        const int row = r0 + wr*64 + fm*16 + lg*4 + r;
        float v = acc[fm][fn][r] + bv;
        if (ACT==1) v = fmaxf(v, 0.f);
        const size_t idx = (size_t)row*N + col;
        if (OMODE==0) Cf[idx] = v;
        else if (OMODE==1) Ch[idx] = __float2bfloat16(v);
        else split_store(Ch, Cl, idx, v);
      }
    }
  }
}

// ---------------- attention coefficients ----------------
__global__ __launch_bounds__(256) void alsald_kernel(const bf16* __restrict__ h,
    const float* __restrict__ a_s, const float* __restrict__ a_d,
    float* __restrict__ als, float* __restrict__ ald){
  int n = blockIdx.x;
  int w = threadIdx.x >> 6, lane = threadIdx.x & 63;
  int c = w*128 + lane*2;
  bf162 hv = *(const bf162*)&h[(size_t)n*FEAT + c];
  float hx = __bfloat162float(hv.x), hy = __bfloat162float(hv.y);
  float2 as2 = *(const float2*)&a_s[c];
  float2 ad2 = *(const float2*)&a_d[c];
  float s = hx*as2.x + hy*as2.y;
  float d = hx*ad2.x + hy*ad2.y;
#pragma unroll
  for (int o=32;o>0;o>>=1){ s += __shfl_xor(s,o); d += __shfl_xor(d,o); }
  if (lane == 0){ als[n*4+w] = s; ald[n*4+w] = d; }
}

// ---------------- fused GAT aggregation (r18-measured: packed alpha, 2-deep pipeline) ----------------
template<bool CONCAT>
__global__ __launch_bounds__(256) void gat_fused_kernel(const bf16* __restrict__ hfeat,
    const float* __restrict__ als, const float* __restrict__ ald,
    const int* __restrict__ offs, const unsigned short* __restrict__ csr,
    const float* __restrict__ bias, void* __restrict__ outv,
    bf16* __restrict__ qh, bf16* __restrict__ ql){
  const int w = threadIdx.x >> 6, l = threadIdx.x & 63, g = l >> 4, s16 = l & 15;
  const int nb = blockIdx.x;
  const int n = (nb & 7)*2048 + (nb >> 3)*4 + w;   // cluster-contiguous, XCD-aligned
  const float adg = ald[(size_t)n*4 + g];
  const int beg = offs[n];
  const int cnt = offs[n+1] - beg + 1;             // + implicit self-loop (edge cnt-1)
  float ev[6]; int sv[6];
#pragma unroll
  for (int p=0;p<6;p++){
    const int i = s16 + p*16;
    int src = n;
    float e = -1e30f;
    if (i < cnt){
      if (i < cnt-1) src = (int)csr[beg+i];
      float t = als[(size_t)src*4+g] + adg;
      e = fmaxf(t, 0.2f*t);                        // leaky_relu 0.2
    }
    ev[p] = e; sv[p] = src;
  }
  float m = -1e30f;
#pragma unroll
  for (int p=0;p<6;p++) m = fmaxf(m, ev[p]);
  float den = 0.f;
#pragma unroll
  for (int p=0;p<6;p++) den += (ev[p] > -1e29f) ? __expf(ev[p]-m) : 0.f;
#pragma unroll
  for (int mask=1; mask<16; mask<<=1){
    float mo = __shfl_xor(m, mask);
    float dd = __shfl_xor(den, mask);
    float nm = fmaxf(m, mo);
    den = den*__expf(m-nm) + dd*__expf(mo-nm);
    m = nm;
  }
  const float C = __expf(-m)/(den + 1e-16f);
  int pk[6];
#pragma unroll
  for (int p=0;p<6;p++){
    float a = (ev[p] > -1e29f) ? __expf(ev[p])*C : 0.f;
    bf16 ab = __float2bfloat16(a);
    pk[p] = ((int)*(unsigned short*)&ab << 16) | (sv[p] & 0xFFFF);
  }
  float acc[8] = {0,0,0,0,0,0,0,0};
  const int fb = l*8;
  const bf16* hp = hfeat + fb;
#pragma unroll
  for (int p=0;p<6;p++){
    const int pbase = p*16;
    if (pbase < cnt){
      const int lim = (cnt - pbase < 16) ? (cnt - pbase) : 16;
      int u_c = __shfl(pk[p], (l & 48));
      short8v hv_c = *(const short8v*)(const void*)(hp + (size_t)(u_c & 0xFFFF)*FEAT);
      for (int j=1; j<lim; ++j){
        const int u_n = __shfl(pk[p], (l & 48) | j);
        const short8v hv_n = *(const short8v*)(const void*)(hp + (size_t)(u_n & 0xFFFF)*FEAT);
        const float a_c = __uint_as_float((unsigned)u_c & 0xFFFF0000u);
#pragma unroll
        for (int k=0;k<8;k++) acc[k] += a_c * b2f(hv_c[k]);
        u_c = u_n; hv_c = hv_n;
      }
      const float a_c = __uint_as_float((unsigned)u_c & 0xFFFF0000u);
#pragma unroll
      for (int k=0;k<8;k++) acc[k] += a_c * b2f(hv_c[k]);
    }
  }
  for (int i = 96; i < cnt; ++i){
    const int src = (i < cnt-1) ? (int)csr[beg+i] : n;
    float t = als[(size_t)src*4+g] + adg;
    t = fmaxf(t, 0.2f*t);
    const float a = __expf(t)*C;
    const short8v hv = *(const short8v*)(const void*)&hfeat[(size_t)src*FEAT + fb];
#pragma unroll
    for (int k=0;k<8;k++) acc[k] += a * b2f(hv[k]);
  }
  if (CONCAT){
    short8v ov;
#pragma unroll
    for (int j=0;j<8;j++){
      float v = acc[j] + bias[fb+j];
      v = v > 0.f ? v : expm1f(v);               // fused ELU
      bf16 bv = __float2bfloat16(v);
      ov[j] = (short)*(unsigned short*)&bv;
    }
    *(short8v*)((char*)outv + ((size_t)n*FEAT + fb)*2) = ov;
  } else {
#pragma unroll
    for (int j=0;j<8;j++){
      acc[j] += __shfl_xor(acc[j], 16);
      acc[j] += __shfl_xor(acc[j], 32);
    }
    if (l < 16){
      float* op = (float*)outv + (size_t)n*128 + l*8;
#pragma unroll
      for (int j=0;j<8;j++){
        const int col = l*8 + j;
        float v = 0.25f*acc[j] + bias[col];
        float ex = __expf((float)(col & ~1) * (-9.210340371976184f/128.f));
        float pe = (col & 1) ? cosf(4.f*ex) : sinf(4.f*ex);
        float q = v + pe;
        op[j] = q;
        split_store(qh, ql, (size_t)n*128 + col, q);
      }
    }
  }
}

// ---------------- LayerNorm(a+b), optional bf16 split output ----------------
template<int SPLIT>
__global__ __launch_bounds__(256) void ln_kernel(const float* __restrict__ a, const float* __restrict__ b,
    const float* __restrict__ g, const float* __restrict__ bb, float* __restrict__ out,
    bf16* __restrict__ oh, bf16* __restrict__ ol){
  int row = blockIdx.x*4 + (threadIdx.x >> 6);
  int lane = threadIdx.x & 63;
  int c = lane*2;
  float2 va = *(const float2*)&a[(size_t)row*128 + c];
  float2 vb = *(const float2*)&b[(size_t)row*128 + c];
  float x0 = va.x+vb.x, x1 = va.y+vb.y;
  float s = x0+x1, q = x0*x0 + x1*x1;
#pragma unroll
  for (int o=32;o>0;o>>=1){ s += __shfl_xor(s,o); q += __shfl_xor(q,o); }
  float mu = s*(1.f/128.f);
  float var = q*(1.f/128.f) - mu*mu;
  float r = 1.f/sqrtf(var + 1e-5f);
  float y0 = (x0-mu)*r*g[c]   + bb[c];
  float y1 = (x1-mu)*r*g[c+1] + bb[c+1];
  size_t idx = (size_t)row*128 + c;
  out[idx] = y0; out[idx+1] = y1;
  if (SPLIT){ split_store(oh, ol, idx, y0); split_store(oh, ol, idx+1, y1); }
}

// ---------------- fused LayerNorm2 + classifier head ----------------
__global__ __launch_bounds__(256) void ln_final_kernel(const float* __restrict__ a, const float* __restrict__ b,
    const float* __restrict__ g, const float* __restrict__ bb,
    const float* __restrict__ wc, const float* __restrict__ bc,
    float* __restrict__ out){
  int row = blockIdx.x*4 + (threadIdx.x >> 6);
  int lane = threadIdx.x & 63;
  int c = lane*2;
  float2 va = *(const float2*)&a[(size_t)row*128 + c];
  float2 vb = *(const float2*)&b[(size_t)row*128 + c];
  float x0 = va.x+vb.x, x1 = va.y+vb.y;
  float s = x0+x1, q = x0*x0 + x1*x1;
#pragma unroll
  for (int o=32;o>0;o>>=1){ s += __shfl_xor(s,o); q += __shfl_xor(q,o); }
  float mu = s*(1.f/128.f);
  float var = q*(1.f/128.f) - mu*mu;
  float r = 1.f/sqrtf(var + 1e-5f);
  float y0 = (x0-mu)*r*g[c]   + bb[c];
  float y1 = (x1-mu)*r*g[c+1] + bb[c+1];
  float s0 = y0*wc[c*2]   + y1*wc[(c+1)*2];
  float s1 = y0*wc[c*2+1] + y1*wc[(c+1)*2+1];
#pragma unroll
  for (int o=32;o>0;o>>=1){ s0 += __shfl_xor(s0,o); s1 += __shfl_xor(s1,o); }
  if (lane == 0){
    out[row*2]   = s0 + bc[0];
    out[row*2+1] = s1 + bc[1];
  }
}

extern "C" void kernel_launch(void* const* d_in, const int* in_sizes, int n_in,
                              void* d_out, int out_size, void* d_ws, size_t ws_size,
                              hipStream_t stream){
  const float* x      = (const float*)d_in[0];
  const int*   ei     = (const int*)d_in[1];
  const float* W1     = (const float*)d_in[3];
  const float* a_src1 = (const float*)d_in[4];
  const float* a_dst1 = (const float*)d_in[5];
  const float* b1     = (const float*)d_in[6];
  const float* W2     = (const float*)d_in[7];
  const float* a_src2 = (const float*)d_in[8];
  const float* a_dst2 = (const float*)d_in[9];
  const float* b2     = (const float*)d_in[10];
  const float* wv     = (const float*)d_in[15];
  const float* bv     = (const float*)d_in[16];
  const float* wo     = (const float*)d_in[17];
  const float* bo     = (const float*)d_in[18];
  const float* ln_g   = (const float*)d_in[19];
  const float* ln_b   = (const float*)d_in[20];
  const float* f1     = (const float*)d_in[21];
  const float* fb1    = (const float*)d_in[22];
  const float* f2     = (const float*)d_in[23];
  const float* fb2    = (const float*)d_in[24];
  const float* wc     = (const float*)d_in[25];
  const float* bc     = (const float*)d_in[26];
  float* outp = (float*)d_out;

  const int E = in_sizes[1] / 2;
  const int n = NODES;
  const int tE = 2*E;
  const size_t MB = 1024*1024;

  const size_t NEED = 36*MB;
  if (ws_size < NEED){
    sentinel_kernel<<<(out_size+255)/256, 256, 0, stream>>>(outp, out_size,
        1000.0f + (float)(ws_size / MB));
    return;
  }

  // ---- arena [0,36) MB ----
  char* base = (char*)d_ws;
  int* counts = (int*)(base + 0);
  int* cursor = (int*)(base + 65536);
  bf16*  h1    = (bf16*)(base + 0);          // [0,16)
  bf16*  xh    = (bf16*)(base + 16*MB);      // [16,20)
  bf16*  h     = (bf16*)(base + 16*MB);      // [16,32)
  bf16*  h2f   = (bf16*)(base + 0);          // [0,16)
  float* h2q   = (float*)(base + 16*MB);     // [16,24)
  bf16*  qh    = (bf16*)(base + 24*MB);      // [24,28)
  bf16*  ql    = (bf16*)(base + 28*MB);      // [28,32)
  bf16*  vh    = (bf16*)(base + 0);          // [0,4)
  bf16*  vl    = (bf16*)(base + 4*MB);       // [4,8)
  float* aobuf = (float*)(base + 8*MB);      // [8,16)
  float* y1    = (float*)(base + 24*MB);     // [24,32)
  bf16*  y1h   = (bf16*)(base + 0);          // [0,4)
  bf16*  y1l   = (bf16*)(base + 4*MB);       // [4,8)
  bf16*  hidden= (bf16*)(base + 8*MB);       // [8,24)
  float* ffn2f = (float*)(base + 0);         // [0,8)
  char* u = base + 32*MB;
  bf16* w1h = (bf16*)u; u += 131072;
  bf16* w2h = (bf16*)u; u += 524288;
  bf16* wvh = (bf16*)u; u += 32768;   bf16* wvl = (bf16*)u; u += 32768;
  bf16* woh = (bf16*)u; u += 32768;   bf16* wol = (bf16*)u; u += 32768;
  bf16* f1h = (bf16*)u; u += 131072;  bf16* f1l = (bf16*)u; u += 131072;
  bf16* f2h = (bf16*)u; u += 131072;  bf16* f2l = (bf16*)u; u += 131072;
  float* als  = (float*)u; u += (size_t)n*4*4;
  float* ald  = (float*)u; u += (size_t)n*4*4;
  int* offs   = (int*)u;   u += (size_t)(n+1)*4 + 252;
  unsigned short* csr = (unsigned short*)u; u += (size_t)tE*2;

  // ---- prep + CSR ----
  PrepArgs P = { x,W1,W2,wv,wo,f1,f2, xh,w1h,w2h,wvh,wvl,woh,wol,f1h,f1l,f2h,f2l };
  prep_kernel<<<632, 256, 0, stream>>>(P);
  zero_kernel<<<(n+255)/256, 256, 0, stream>>>(counts, n);
  count_kernel<<<(tE+255)/256, 256, 0, stream>>>(ei, counts, E);
  scan_kernel<<<1, 1024, 0, stream>>>(counts, offs, cursor);
  fill_kernel<<<(tE+255)/256, 256, 0, stream>>>(ei, cursor, csr, E);

  // ---- GAT layer 1 ----
  lgemm<128,0,0,0,1><<<dim3(128,4), 256, 0, stream>>>(xh, nullptr, w1h, nullptr, nullptr, nullptr, h1, nullptr, 512);
  alsald_kernel<<<n, 256, 0, stream>>>(h1, a_src1, a_dst1, als, ald);
  gat_fused_kernel<true><<<n/4, 256, 0, stream>>>(h1, als, ald, offs, csr, b1, h, nullptr, nullptr);

  // ---- GAT layer 2 ----
  lgemm<512,0,0,0,1><<<dim3(128,4), 256, 0, stream>>>(h, nullptr, w2h, nullptr, nullptr, nullptr, h2f, nullptr, 512);
  alsald_kernel<<<n, 256, 0, stream>>>(h2f, a_src2, a_dst2, als, ald);
  gat_fused_kernel<false><<<n/4, 256, 0, stream>>>(h2f, als, ald, offs, csr, b2, h2q, qh, ql);

  // ---- temporal attention (collapsed to V at l=L-1) + head: split-precision tail ----
  lgemm<128,1,1,0,2><<<dim3(128,1), 256, 0, stream>>>(qh, ql, wvh, wvl, bv, nullptr, vh, vl, 128);
  lgemm<128,1,1,0,0><<<dim3(128,1), 256, 0, stream>>>(vh, vl, woh, wol, bo, aobuf, nullptr, nullptr, 128);
  ln_kernel<1><<<n/4, 256, 0, stream>>>(h2q, aobuf, ln_g, ln_b, y1, y1h, y1l);
  lgemm<128,1,1,1,1><<<dim3(128,4), 256, 0, stream>>>(y1h, y1l, f1h, f1l, fb1, nullptr, hidden, nullptr, 512);
  lgemm<512,0,1,0,0><<<dim3(128,1), 256, 0, stream>>>(hidden, nullptr, f2h, f2l, fb2, ffn2f, nullptr, nullptr, 128);
  ln_final_kernel<<<n/4, 256, 0, stream>>>(y1, ffn2f, ln_g, ln_b, wc, bc, outp);
}

// Round 21
// 264.226 us; speedup vs baseline: 1.1498x; 1.0549x over previous
//
#include <hip/hip_runtime.h>
#include <hip/hip_bf16.h>

#define NODES 16384
#define FEAT 512
typedef __hip_bfloat16 bf16;
typedef __hip_bfloat162 bf162;
typedef short short8v __attribute__((ext_vector_type(8)));
typedef float f32x4 __attribute__((ext_vector_type(4)));

static __device__ __forceinline__ float b2f(short s){
  return __uint_as_float(((unsigned)(unsigned short)s) << 16);
}
static __device__ __forceinline__ void split_store(bf16* h, bf16* l, size_t i, float v){
  bf16 hi = __float2bfloat16(v);
  h[i] = hi; l[i] = __float2bfloat16(v - __bfloat162float(hi));
}

// ---------------- diagnostic sentinel ----------------
__global__ void sentinel_kernel(float* __restrict__ out, int n, float v){
  int i = blockIdx.x*blockDim.x + threadIdx.x;
  if (i < n) out[i] = v;
}

// ---------------- CSR build ----------------
__global__ void zero_kernel(int* __restrict__ p, int n){
  int i = blockIdx.x*blockDim.x + threadIdx.x;
  if (i < n) p[i] = 0;
}
__global__ void count_kernel(const int* __restrict__ ei, int* __restrict__ counts, int E){
  int i = blockIdx.x*blockDim.x + threadIdx.x;
  if (i < 2*E){
    int dst = (i < E) ? ei[E+i] : ei[i-E];
    atomicAdd(&counts[dst], 1);
  }
}
__global__ __launch_bounds__(1024) void scan_kernel(const int* __restrict__ counts,
                                                    int* __restrict__ offs, int* __restrict__ cursor){
  __shared__ int sh[1024];
  const int t = threadIdx.x;
  int loc[16]; int s = 0;
#pragma unroll
  for (int i=0;i<16;i++){ loc[i] = counts[t*16+i]; s += loc[i]; }
  sh[t] = s; __syncthreads();
  for (int d=1; d<1024; d<<=1){
    int v = (t>=d) ? sh[t-d] : 0;
    __syncthreads(); sh[t] += v; __syncthreads();
  }
  int run = (t==0) ? 0 : sh[t-1];
#pragma unroll
  for (int i=0;i<16;i++){ offs[t*16+i] = run; cursor[t*16+i] = run; run += loc[i]; }
  if (t==1023) offs[NODES] = run;
}
__global__ void fill_kernel(const int* __restrict__ ei, int* __restrict__ cursor,
                            unsigned short* __restrict__ csr, int E){
  int i = blockIdx.x*blockDim.x + threadIdx.x;
  if (i < 2*E){
    int src = ei[i];
    int dst = (i < E) ? ei[E+i] : ei[i-E];
    int pos = atomicAdd(&cursor[dst], 1);
    csr[pos] = (unsigned short)src;
  }
}

// ---------------- prep: x cast + LDS-tiled transpose-cast of all weights ----------------
struct PrepArgs {
  const float *x,*W1,*W2,*wv,*wo,*f1,*f2;
  bf16 *xh,*w1h,*w2h,*wvh,*wvl,*woh,*wol,*f1h,*f1l,*f2h,*f2l;
};
__global__ __launch_bounds__(256) void prep_kernel(PrepArgs P){
  const int b = blockIdx.x;
  const int t = threadIdx.x;
  if (b < 512){
    const size_t base = (size_t)b*4096;
#pragma unroll
    for (int k=0;k<16;k++){
      const size_t i = base + t + 256*k;
      P.xh[i] = __float2bfloat16(P.x[i]);
    }
    return;
  }
  __shared__ float tile[64][65];
  const float* src; bf16 *dh; bf16 *dl; int R, C, ti;
  int bb = b - 512;
  if (bb < 16){ src=P.W1; dh=P.w1h; dl=nullptr; R=128; C=512; ti=bb; }
  else if ((bb-=16) < 64){ src=P.W2; dh=P.w2h; dl=nullptr; R=512; C=512; ti=bb; }
  else if ((bb-=64) < 4){ src=P.wv; dh=P.wvh; dl=P.wvl; R=128; C=128; ti=bb; }
  else if ((bb-=4) < 4){ src=P.wo; dh=P.woh; dl=P.wol; R=128; C=128; ti=bb; }
  else if ((bb-=4) < 16){ src=P.f1; dh=P.f1h; dl=P.f1l; R=128; C=512; ti=bb; }
  else { bb-=16; src=P.f2; dh=P.f2h; dl=P.f2l; R=512; C=128; ti=bb; }
  const int ctiles = C/64;
  const int r0 = (ti/ctiles)*64, c0 = (ti%ctiles)*64;
  const int r = t >> 6, c = t & 63;
#pragma unroll
  for (int i=0;i<16;i++)
    tile[r + 4*i][c] = src[(size_t)(r0 + r + 4*i)*C + c0 + c];
  __syncthreads();
#pragma unroll
  for (int i=0;i<16;i++){
    const int oc   = c0 + r + 4*i;
    const int orow = r0 + c;
    const float v = tile[c][r + 4*i];
    const size_t oi = (size_t)oc*R + orow;
    if (dl){ split_store(dh, dl, oi, v); } else { dh[oi] = __float2bfloat16(v); }
  }
}

static __device__ __forceinline__ short8v ld8(const bf16* p){
  return *(const short8v*)(const void*)(p);
}

// ---------------- LDS-staged MFMA GEMM: 128x128 tile, 4 waves, split-capable ----------------
// ALS=1 (requires OMODE==1, N==512): fused per-(row,head) attention-coefficient dot
// als[n*4+head] = sum_col bf16(C[n][col])*a_s[col], head = blockIdx.y (128-col tile == head).
template<int K, int SA, int SB, int ACT, int OMODE, int ALS>
__global__ __launch_bounds__(256) void lgemm(
    const bf16* __restrict__ A, const bf16* __restrict__ Al,
    const bf16* __restrict__ B, const bf16* __restrict__ Bl,
    const float* __restrict__ bias,
    float* __restrict__ Cf, bf16* __restrict__ Ch, bf16* __restrict__ Cl, int N,
    const float* __restrict__ as_p, const float* __restrict__ ad_p,
    float* __restrict__ als_p, float* __restrict__ ald_p){
  __shared__ bf16 As[128*40];
  __shared__ bf16 Bs[128*40];
  __shared__ bf16 Asl[SA ? 128*40 : 1];
  __shared__ bf16 Bsl[SB ? 128*40 : 1];
  const int tid = threadIdx.x;
  const int l = tid & 63, w = tid >> 6;
  const int lg = l >> 4, lr = l & 15;
  const int wr = w >> 1, wc = w & 1;
  const int r0 = blockIdx.x*128;
  const int c0 = blockIdx.y*128;
  const int srow = tid >> 1;
  const int spos = (tid & 1) * 16;
  f32x4 acc[4][4] = {};
  const int ard[4] = { (wr*64 +  0 + lr)*40 + lg*8, (wr*64 + 16 + lr)*40 + lg*8,
                       (wr*64 + 32 + lr)*40 + lg*8, (wr*64 + 48 + lr)*40 + lg*8 };
  const int brd[4] = { (wc*64 +  0 + lr)*40 + lg*8, (wc*64 + 16 + lr)*40 + lg*8,
                       (wc*64 + 32 + lr)*40 + lg*8, (wc*64 + 48 + lr)*40 + lg*8 };
  const size_t agbase = (size_t)(r0 + srow)*K + spos;
  const size_t bgbase = (size_t)(c0 + srow)*K + spos;
  const int sl = srow*40 + spos;
#pragma unroll
  for (int k0 = 0; k0 < K; k0 += 32){
    *(short8v*)&As[sl]     = ld8(A + agbase + k0);
    *(short8v*)&As[sl + 8] = ld8(A + agbase + k0 + 8);
    *(short8v*)&Bs[sl]     = ld8(B + bgbase + k0);
    *(short8v*)&Bs[sl + 8] = ld8(B + bgbase + k0 + 8);
    if (SA){
      *(short8v*)&Asl[sl]     = ld8(Al + agbase + k0);
      *(short8v*)&Asl[sl + 8] = ld8(Al + agbase + k0 + 8);
    }
    if (SB){
      *(short8v*)&Bsl[sl]     = ld8(Bl + bgbase + k0);
      *(short8v*)&Bsl[sl + 8] = ld8(Bl + bgbase + k0 + 8);
    }
    __syncthreads();
    short8v af[4], bfr[4], afl[4], bfl[4];
#pragma unroll
    for (int f=0; f<4; f++){
      af[f]  = *(const short8v*)&As[ard[f]];
      bfr[f] = *(const short8v*)&Bs[brd[f]];
      if (SA) afl[f] = *(const short8v*)&Asl[ard[f]];
      if (SB) bfl[f] = *(const short8v*)&Bsl[brd[f]];
    }
#pragma unroll
    for (int fm=0; fm<4; fm++)
#pragma unroll
      for (int fn=0; fn<4; fn++){
        acc[fm][fn] = __builtin_amdgcn_mfma_f32_16x16x32_bf16(af[fm], bfr[fn], acc[fm][fn], 0,0,0);
        if (SB) acc[fm][fn] = __builtin_amdgcn_mfma_f32_16x16x32_bf16(af[fm], bfl[fn], acc[fm][fn], 0,0,0);
        if (SA) acc[fm][fn] = __builtin_amdgcn_mfma_f32_16x16x32_bf16(afl[fm], bfr[fn], acc[fm][fn], 0,0,0);
      }
    __syncthreads();
  }
  float asv[4], adv[4];
  float rs[4][4], rd[4][4];
  if (ALS){
#pragma unroll
    for (int fn=0; fn<4; fn++){
      const int col = c0 + wc*64 + fn*16 + lr;
      asv[fn] = as_p[col]; adv[fn] = ad_p[col];
    }
#pragma unroll
    for (int fm=0; fm<4; fm++)
#pragma unroll
      for (int r=0; r<4; r++){ rs[fm][r] = 0.f; rd[fm][r] = 0.f; }
  }
#pragma unroll
  for (int fm=0; fm<4; fm++){
#pragma unroll
    for (int fn=0; fn<4; fn++){
      const int col = c0 + wc*64 + fn*16 + lr;
      const float bv = bias ? bias[col] : 0.f;
#pragma unroll
      for (int r=0; r<4; r++){
        const int row = r0 + wr*64 + fm*16 + lg*4 + r;
        float v = acc[fm][fn][r] + bv;
        if (ACT==1) v = fmaxf(v, 0.f);
        const size_t idx = (size_t)row*N + col;
        if (OMODE==0) Cf[idx] = v;
        else if (OMODE==1){
          bf16 bvv = __float2bfloat16(v);
          Ch[idx] = bvv;
          if (ALS){
            const float hv = __bfloat162float(bvv);   // rounded value == what agg reads
            rs[fm][r] += hv*asv[fn];
            rd[fm][r] += hv*adv[fn];
          }
        }
        else split_store(Ch, Cl, idx, v);
      }
    }
  }
  if (ALS){
    float* rb = (float*)As;   // reuse LDS (all MFMA reads done)
#pragma unroll
    for (int fm=0; fm<4; fm++)
#pragma unroll
      for (int r=0; r<4; r++){
        float s = rs[fm][r], dd = rd[fm][r];
#pragma unroll
        for (int mask=1; mask<16; mask<<=1){
          s  += __shfl_xor(s,  mask);
          dd += __shfl_xor(dd, mask);
        }
        rs[fm][r] = s; rd[fm][r] = dd;
      }
    if (wc == 1 && lr == 0){
#pragma unroll
      for (int fm=0; fm<4; fm++)
#pragma unroll
        for (int r=0; r<4; r++){
          const int row = wr*64 + fm*16 + lg*4 + r;
          rb[row] = rs[fm][r]; rb[128+row] = rd[fm][r];
        }
    }
    __syncthreads();
    if (wc == 0 && lr == 0){
      const int head = blockIdx.y;
#pragma unroll
      for (int fm=0; fm<4; fm++)
#pragma unroll
        for (int r=0; r<4; r++){
          const int row = wr*64 + fm*16 + lg*4 + r;
          als_p[(size_t)(r0+row)*4 + head] = rs[fm][r] + rb[row];
          ald_p[(size_t)(r0+row)*4 + head] = rd[fm][r] + rb[128+row];
        }
    }
  }
}

// ---------------- fused GAT aggregation (r18-measured: packed alpha, 2-deep pipeline) ----------------
template<bool CONCAT>
__global__ __launch_bounds__(256) void gat_fused_kernel(const bf16* __restrict__ hfeat,
    const float* __restrict__ als, const float* __restrict__ ald,
    const int* __restrict__ offs, const unsigned short* __restrict__ csr,
    const float* __restrict__ bias, void* __restrict__ outv,
    bf16* __restrict__ qh, bf16* __restrict__ ql){
  const int w = threadIdx.x >> 6, l = threadIdx.x & 63, g = l >> 4, s16 = l & 15;
  const int nb = blockIdx.x;
  const int n = (nb & 7)*2048 + (nb >> 3)*4 + w;   // cluster-contiguous, XCD-aligned
  const float adg = ald[(size_t)n*4 + g];
  const int beg = offs[n];
  const int cnt = offs[n+1] - beg + 1;             // + implicit self-loop (edge cnt-1)
  float ev[6]; int sv[6];
#pragma unroll
  for (int p=0;p<6;p++){
    const int i = s16 + p*16;
    int src = n;
    float e = -1e30f;
    if (i < cnt){
      if (i < cnt-1) src = (int)csr[beg+i];
      float t = als[(size_t)src*4+g] + adg;
      e = fmaxf(t, 0.2f*t);                        // leaky_relu 0.2
    }
    ev[p] = e; sv[p] = src;
  }
  float m = -1e30f;
#pragma unroll
  for (int p=0;p<6;p++) m = fmaxf(m, ev[p]);
  float den = 0.f;
#pragma unroll
  for (int p=0;p<6;p++) den += (ev[p] > -1e29f) ? __expf(ev[p]-m) : 0.f;
#pragma unroll
  for (int mask=1; mask<16; mask<<=1){
    float mo = __shfl_xor(m, mask);
    float dd = __shfl_xor(den, mask);
    float nm = fmaxf(m, mo);
    den = den*__expf(m-nm) + dd*__expf(mo-nm);
    m = nm;
  }
  const float C = __expf(-m)/(den + 1e-16f);
  int pk[6];
#pragma unroll
  for (int p=0;p<6;p++){
    float a = (ev[p] > -1e29f) ? __expf(ev[p])*C : 0.f;
    bf16 ab = __float2bfloat16(a);
    pk[p] = ((int)*(unsigned short*)&ab << 16) | (sv[p] & 0xFFFF);
  }
  float acc[8] = {0,0,0,0,0,0,0,0};
  const int fb = l*8;
  const bf16* hp = hfeat + fb;
#pragma unroll
  for (int p=0;p<6;p++){
    const int pbase = p*16;
    if (pbase < cnt){
      const int lim = (cnt - pbase < 16) ? (cnt - pbase) : 16;
      int u_c = __shfl(pk[p], (l & 48));
      short8v hv_c = *(const short8v*)(const void*)(hp + (size_t)(u_c & 0xFFFF)*FEAT);
      for (int j=1; j<lim; ++j){
        const int u_n = __shfl(pk[p], (l & 48) | j);
        const short8v hv_n = *(const short8v*)(const void*)(hp + (size_t)(u_n & 0xFFFF)*FEAT);
        const float a_c = __uint_as_float((unsigned)u_c & 0xFFFF0000u);
#pragma unroll
        for (int k=0;k<8;k++) acc[k] += a_c * b2f(hv_c[k]);
        u_c = u_n; hv_c = hv_n;
      }
      const float a_c = __uint_as_float((unsigned)u_c & 0xFFFF0000u);
#pragma unroll
      for (int k=0;k<8;k++) acc[k] += a_c * b2f(hv_c[k]);
    }
  }
  for (int i = 96; i < cnt; ++i){
    const int src = (i < cnt-1) ? (int)csr[beg+i] : n;
    float t = als[(size_t)src*4+g] + adg;
    t = fmaxf(t, 0.2f*t);
    const float a = __expf(t)*C;
    const short8v hv = *(const short8v*)(const void*)&hfeat[(size_t)src*FEAT + fb];
#pragma unroll
    for (int k=0;k<8;k++) acc[k] += a * b2f(hv[k]);
  }
  if (CONCAT){
    short8v ov;
#pragma unroll
    for (int j=0;j<8;j++){
      float v = acc[j] + bias[fb+j];
      v = v > 0.f ? v : expm1f(v);               // fused ELU
      bf16 bv = __float2bfloat16(v);
      ov[j] = (short)*(unsigned short*)&bv;
    }
    *(short8v*)((char*)outv + ((size_t)n*FEAT + fb)*2) = ov;
  } else {
#pragma unroll
    for (int j=0;j<8;j++){
      acc[j] += __shfl_xor(acc[j], 16);
      acc[j] += __shfl_xor(acc[j], 32);
    }
    if (l < 16){
      float* op = (float*)outv + (size_t)n*128 + l*8;
#pragma unroll
      for (int j=0;j<8;j++){
        const int col = l*8 + j;
        float v = 0.25f*acc[j] + bias[col];
        float ex = __expf((float)(col & ~1) * (-9.210340371976184f/128.f));
        float pe = (col & 1) ? cosf(4.f*ex) : sinf(4.f*ex);
        float q = v + pe;
        op[j] = q;
        split_store(qh, ql, (size_t)n*128 + col, q);
      }
    }
  }
}

// ---------------- LayerNorm(a+b), optional bf16 split output ----------------
template<int SPLIT>
__global__ __launch_bounds__(256) void ln_kernel(const float* __restrict__ a, const float* __restrict__ b,
    const float* __restrict__ g, const float* __restrict__ bb, float* __restrict__ out,
    bf16* __restrict__ oh, bf16* __restrict__ ol){
  int row = blockIdx.x*4 + (threadIdx.x >> 6);
  int lane = threadIdx.x & 63;
  int c = lane*2;
  float2 va = *(const float2*)&a[(size_t)row*128 + c];
  float2 vb = *(const float2*)&b[(size_t)row*128 + c];
  float x0 = va.x+vb.x, x1 = va.y+vb.y;
  float s = x0+x1, q = x0*x0 + x1*x1;
#pragma unroll
  for (int o=32;o>0;o>>=1){ s += __shfl_xor(s,o); q += __shfl_xor(q,o); }
  float mu = s*(1.f/128.f);
  float var = q*(1.f/128.f) - mu*mu;
  float r = 1.f/sqrtf(var + 1e-5f);
  float y0 = (x0-mu)*r*g[c]   + bb[c];
  float y1 = (x1-mu)*r*g[c+1] + bb[c+1];
  size_t idx = (size_t)row*128 + c;
  out[idx] = y0; out[idx+1] = y1;
  if (SPLIT){ split_store(oh, ol, idx, y0); split_store(oh, ol, idx+1, y1); }
}

// ---------------- fused LayerNorm2 + classifier head ----------------
__global__ __launch_bounds__(256) void ln_final_kernel(const float* __restrict__ a, const float* __restrict__ b,
    const float* __restrict__ g, const float* __restrict__ bb,
    const float* __restrict__ wc, const float* __restrict__ bc,
    float* __restrict__ out){
  int row = blockIdx.x*4 + (threadIdx.x >> 6);
  int lane = threadIdx.x & 63;
  int c = lane*2;
  float2 va = *(const float2*)&a[(size_t)row*128 + c];
  float2 vb = *(const float2*)&b[(size_t)row*128 + c];
  float x0 = va.x+vb.x, x1 = va.y+vb.y;
  float s = x0+x1, q = x0*x0 + x1*x1;
#pragma unroll
  for (int o=32;o>0;o>>=1){ s += __shfl_xor(s,o); q += __shfl_xor(q,o); }
  float mu = s*(1.f/128.f);
  float var = q*(1.f/128.f) - mu*mu;
  float r = 1.f/sqrtf(var + 1e-5f);
  float y0 = (x0-mu)*r*g[c]   + bb[c];
  float y1 = (x1-mu)*r*g[c+1] + bb[c+1];
  float s0 = y0*wc[c*2]   + y1*wc[(c+1)*2];
  float s1 = y0*wc[c*2+1] + y1*wc[(c+1)*2+1];
#pragma unroll
  for (int o=32;o>0;o>>=1){ s0 += __shfl_xor(s0,o); s1 += __shfl_xor(s1,o); }
  if (lane == 0){
    out[row*2]   = s0 + bc[0];
    out[row*2+1] = s1 + bc[1];
  }
}

extern "C" void kernel_launch(void* const* d_in, const int* in_sizes, int n_in,
                              void* d_out, int out_size, void* d_ws, size_t ws_size,
                              hipStream_t stream){
  const float* x      = (const float*)d_in[0];
  const int*   ei     = (const int*)d_in[1];
  const float* W1     = (const float*)d_in[3];
  const float* a_src1 = (const float*)d_in[4];
  const float* a_dst1 = (const float*)d_in[5];
  const float* b1     = (const float*)d_in[6];
  const float* W2     = (const float*)d_in[7];
  const float* a_src2 = (const float*)d_in[8];
  const float* a_dst2 = (const float*)d_in[9];
  const float* b2     = (const float*)d_in[10];
  const float* wv     = (const float*)d_in[15];
  const float* bv     = (const float*)d_in[16];
  const float* wo     = (const float*)d_in[17];
  const float* bo     = (const float*)d_in[18];
  const float* ln_g   = (const float*)d_in[19];
  const float* ln_b   = (const float*)d_in[20];
  const float* f1     = (const float*)d_in[21];
  const float* fb1    = (const float*)d_in[22];
  const float* f2     = (const float*)d_in[23];
  const float* fb2    = (const float*)d_in[24];
  const float* wc     = (const float*)d_in[25];
  const float* bc     = (const float*)d_in[26];
  float* outp = (float*)d_out;

  const int E = in_sizes[1] / 2;
  const int n = NODES;
  const int tE = 2*E;
  const size_t MB = 1024*1024;

  const size_t NEED = 36*MB;
  if (ws_size < NEED){
    sentinel_kernel<<<(out_size+255)/256, 256, 0, stream>>>(outp, out_size,
        1000.0f + (float)(ws_size / MB));
    return;
  }

  // ---- arena [0,36) MB ----
  char* base = (char*)d_ws;
  int* counts = (int*)(base + 0);
  int* cursor = (int*)(base + 65536);
  bf16*  h1    = (bf16*)(base + 0);          // [0,16)
  bf16*  xh    = (bf16*)(base + 16*MB);      // [16,20)
  bf16*  h     = (bf16*)(base + 16*MB);      // [16,32)
  bf16*  h2f   = (bf16*)(base + 0);          // [0,16)
  float* h2q   = (float*)(base + 16*MB);     // [16,24)
  bf16*  qh    = (bf16*)(base + 24*MB);      // [24,28)
  bf16*  ql    = (bf16*)(base + 28*MB);      // [28,32)
  bf16*  vh    = (bf16*)(base + 0);          // [0,4)
  bf16*  vl    = (bf16*)(base + 4*MB);       // [4,8)
  float* aobuf = (float*)(base + 8*MB);      // [8,16)
  float* y1    = (float*)(base + 24*MB);     // [24,32)
  bf16*  y1h   = (bf16*)(base + 0);          // [0,4)
  bf16*  y1l   = (bf16*)(base + 4*MB);       // [4,8)
  bf16*  hidden= (bf16*)(base + 8*MB);       // [8,24)
  float* ffn2f = (float*)(base + 0);         // [0,8)
  char* u = base + 32*MB;
  bf16* w1h = (bf16*)u; u += 131072;
  bf16* w2h = (bf16*)u; u += 524288;
  bf16* wvh = (bf16*)u; u += 32768;   bf16* wvl = (bf16*)u; u += 32768;
  bf16* woh = (bf16*)u; u += 32768;   bf16* wol = (bf16*)u; u += 32768;
  bf16* f1h = (bf16*)u; u += 131072;  bf16* f1l = (bf16*)u; u += 131072;
  bf16* f2h = (bf16*)u; u += 131072;  bf16* f2l = (bf16*)u; u += 131072;
  float* als  = (float*)u; u += (size_t)n*4*4;
  float* ald  = (float*)u; u += (size_t)n*4*4;
  int* offs   = (int*)u;   u += (size_t)(n+1)*4 + 252;
  unsigned short* csr = (unsigned short*)u; u += (size_t)tE*2;

  // ---- prep + CSR ----
  PrepArgs P = { x,W1,W2,wv,wo,f1,f2, xh,w1h,w2h,wvh,wvl,woh,wol,f1h,f1l,f2h,f2l };
  prep_kernel<<<632, 256, 0, stream>>>(P);
  zero_kernel<<<(n+255)/256, 256, 0, stream>>>(counts, n);
  count_kernel<<<(tE+255)/256, 256, 0, stream>>>(ei, counts, E);
  scan_kernel<<<1, 1024, 0, stream>>>(counts, offs, cursor);
  fill_kernel<<<(tE+255)/256, 256, 0, stream>>>(ei, cursor, csr, E);

  // ---- GAT layer 1 (als/ald fused into GEMM epilogue) ----
  lgemm<128,0,0,0,1,1><<<dim3(128,4), 256, 0, stream>>>(xh, nullptr, w1h, nullptr, nullptr,
      nullptr, h1, nullptr, 512, a_src1, a_dst1, als, ald);
  gat_fused_kernel<true><<<n/4, 256, 0, stream>>>(h1, als, ald, offs, csr, b1, h, nullptr, nullptr);

  // ---- GAT layer 2 (als/ald fused) ----
  lgemm<512,0,0,0,1,1><<<dim3(128,4), 256, 0, stream>>>(h, nullptr, w2h, nullptr, nullptr,
      nullptr, h2f, nullptr, 512, a_src2, a_dst2, als, ald);
  gat_fused_kernel<false><<<n/4, 256, 0, stream>>>(h2f, als, ald, offs, csr, b2, h2q, qh, ql);

  // ---- temporal attention (collapsed to V at l=L-1) + head: split-precision tail ----
  lgemm<128,1,1,0,2,0><<<dim3(128,1), 256, 0, stream>>>(qh, ql, wvh, wvl, bv,
      nullptr, vh, vl, 128, nullptr, nullptr, nullptr, nullptr);
  lgemm<128,1,1,0,0,0><<<dim3(128,1), 256, 0, stream>>>(vh, vl, woh, wol, bo,
      aobuf, nullptr, nullptr, 128, nullptr, nullptr, nullptr, nullptr);
  ln_kernel<1><<<n/4, 256, 0, stream>>>(h2q, aobuf, ln_g, ln_b, y1, y1h, y1l);
  lgemm<128,1,1,1,1,0><<<dim3(128,4), 256, 0, stream>>>(y1h, y1l, f1h, f1l, fb1,
      nullptr, hidden, nullptr, 512, nullptr, nullptr, nullptr, nullptr);
  lgemm<512,0,1,0,0,0><<<dim3(128,1), 256, 0, stream>>>(hidden, nullptr, f2h, f2l, fb2,
      ffn2f, nullptr, nullptr, 128, nullptr, nullptr, nullptr, nullptr);
  ln_final_kernel<<<n/4, 256, 0, stream>>>(y1, ffn2f, ln_g, ln_b, wc, bc, outp);
}

// Round 22
// 252.918 us; speedup vs baseline: 1.2012x; 1.0447x over previous
//
#include <hip/hip_runtime.h>
#include <hip/hip_bf16.h>

#define NODES 16384
#define FEAT 512
typedef __hip_bfloat16 bf16;
typedef __hip_bfloat162 bf162;
typedef short short8v __attribute__((ext_vector_type(8)));
typedef unsigned int uint4v __attribute__((ext_vector_type(4)));
typedef float f32x4 __attribute__((ext_vector_type(4)));

static __device__ __forceinline__ float b2f(short s){
  return __uint_as_float(((unsigned)(unsigned short)s) << 16);
}
static __device__ __forceinline__ void split_store(bf16* h, bf16* l, size_t i, float v){
  bf16 hi = __float2bfloat16(v);
  h[i] = hi; l[i] = __float2bfloat16(v - __bfloat162float(hi));
}

// ---------------- diagnostic sentinel ----------------
__global__ void sentinel_kernel(float* __restrict__ out, int n, float v){
  int i = blockIdx.x*blockDim.x + threadIdx.x;
  if (i < n) out[i] = v;
}

// ---------------- CSR build ----------------
__global__ void zero_kernel(int* __restrict__ p, int n){
  int i = blockIdx.x*blockDim.x + threadIdx.x;
  if (i < n) p[i] = 0;
}
__global__ void count_kernel(const int* __restrict__ ei, int* __restrict__ counts, int E){
  int i = blockIdx.x*blockDim.x + threadIdx.x;
  if (i < 2*E){
    int dst = (i < E) ? ei[E+i] : ei[i-E];
    atomicAdd(&counts[dst], 1);
  }
}
__global__ __launch_bounds__(1024) void scan_kernel(const int* __restrict__ counts,
                                                    int* __restrict__ offs, int* __restrict__ cursor){
  __shared__ int sh[1024];
  const int t = threadIdx.x;
  int loc[16]; int s = 0;
#pragma unroll
  for (int i=0;i<16;i++){ loc[i] = counts[t*16+i]; s += loc[i]; }
  sh[t] = s; __syncthreads();
  for (int d=1; d<1024; d<<=1){
    int v = (t>=d) ? sh[t-d] : 0;
    __syncthreads(); sh[t] += v; __syncthreads();
  }
  int run = (t==0) ? 0 : sh[t-1];
#pragma unroll
  for (int i=0;i<16;i++){ offs[t*16+i] = run; cursor[t*16+i] = run; run += loc[i]; }
  if (t==1023) offs[NODES] = run;
}
__global__ void fill_kernel(const int* __restrict__ ei, int* __restrict__ cursor,
                            unsigned short* __restrict__ csr, int E){
  int i = blockIdx.x*blockDim.x + threadIdx.x;
  if (i < 2*E){
    int src = ei[i];
    int dst = (i < E) ? ei[E+i] : ei[i-E];
    int pos = atomicAdd(&cursor[dst], 1);
    csr[pos] = (unsigned short)src;
  }
}

// ---------------- prep: x cast + LDS-tiled transpose-cast of all weights ----------------
struct PrepArgs {
  const float *x,*W1,*W2,*wv,*wo,*f1,*f2;
  bf16 *xh,*w1h,*w2h,*wvh,*wvl,*woh,*wol,*f1h,*f1l,*f2h,*f2l;
};
__global__ __launch_bounds__(256) void prep_kernel(PrepArgs P){
  const int b = blockIdx.x;
  const int t = threadIdx.x;
  if (b < 512){
    const size_t base = (size_t)b*4096;
#pragma unroll
    for (int k=0;k<16;k++){
      const size_t i = base + t + 256*k;
      P.xh[i] = __float2bfloat16(P.x[i]);
    }
    return;
  }
  __shared__ float tile[64][65];
  const float* src; bf16 *dh; bf16 *dl; int R, C, ti;
  int bb = b - 512;
  if (bb < 16){ src=P.W1; dh=P.w1h; dl=nullptr; R=128; C=512; ti=bb; }
  else if ((bb-=16) < 64){ src=P.W2; dh=P.w2h; dl=nullptr; R=512; C=512; ti=bb; }
  else if ((bb-=64) < 4){ src=P.wv; dh=P.wvh; dl=P.wvl; R=128; C=128; ti=bb; }
  else if ((bb-=4) < 4){ src=P.wo; dh=P.woh; dl=P.wol; R=128; C=128; ti=bb; }
  else if ((bb-=4) < 16){ src=P.f1; dh=P.f1h; dl=P.f1l; R=128; C=512; ti=bb; }
  else { bb-=16; src=P.f2; dh=P.f2h; dl=P.f2l; R=512; C=128; ti=bb; }
  const int ctiles = C/64;
  const int r0 = (ti/ctiles)*64, c0 = (ti%ctiles)*64;
  const int r = t >> 6, c = t & 63;
#pragma unroll
  for (int i=0;i<16;i++)
    tile[r + 4*i][c] = src[(size_t)(r0 + r + 4*i)*C + c0 + c];
  __syncthreads();
#pragma unroll
  for (int i=0;i<16;i++){
    const int oc   = c0 + r + 4*i;
    const int orow = r0 + c;
    const float v = tile[c][r + 4*i];
    const size_t oi = (size_t)oc*R + orow;
    if (dl){ split_store(dh, dl, oi, v); } else { dh[oi] = __float2bfloat16(v); }
  }
}

static __device__ __forceinline__ short8v ld8(const bf16* p){
  return *(const short8v*)(const void*)(p);
}

// ---------------- LDS-staged MFMA GEMM: 128x128 tile, 4 waves ----------------
// ALS=1: fused per-(row,head) attention dots (OMODE==1, N==512, head=blockIdx.y).
// LNM=1: fused LayerNorm(qbuf+C+bias) -> y1f (f32) + y1h/y1l bf16 split (N==128, grid.y==1).
// LNM=2: fused LayerNorm(qbuf+C+bias) -> classifier head (wc,bc) -> outp (2 floats/row).
template<int K, int SA, int SB, int ACT, int OMODE, int ALS, int LNM>
__global__ __launch_bounds__(256) void lgemm(
    const bf16* __restrict__ A, const bf16* __restrict__ Al,
    const bf16* __restrict__ B, const bf16* __restrict__ Bl,
    const float* __restrict__ bias,
    float* __restrict__ Cf, bf16* __restrict__ Ch, bf16* __restrict__ Cl, int N,
    const float* __restrict__ as_p, const float* __restrict__ ad_p,
    float* __restrict__ als_p, float* __restrict__ ald_p,
    const float* __restrict__ qbuf, const float* __restrict__ lng, const float* __restrict__ lnb,
    float* __restrict__ y1f, bf16* __restrict__ y1ho, bf16* __restrict__ y1lo,
    const float* __restrict__ wcp, const float* __restrict__ bcp, float* __restrict__ outp){
  __shared__ bf16 As[128*40];
  __shared__ bf16 Bs[128*40];
  __shared__ bf16 Asl[SA ? 128*40 : 1];
  __shared__ bf16 Bsl[SB ? 128*40 : 1];
  const int tid = threadIdx.x;
  const int l = tid & 63, w = tid >> 6;
  const int lg = l >> 4, lr = l & 15;
  const int wr = w >> 1, wc = w & 1;
  const int r0 = blockIdx.x*128;
  const int c0 = blockIdx.y*128;
  const int srow = tid >> 1;
  const int spos = (tid & 1) * 16;
  f32x4 acc[4][4] = {};
  const int ard[4] = { (wr*64 +  0 + lr)*40 + lg*8, (wr*64 + 16 + lr)*40 + lg*8,
                       (wr*64 + 32 + lr)*40 + lg*8, (wr*64 + 48 + lr)*40 + lg*8 };
  const int brd[4] = { (wc*64 +  0 + lr)*40 + lg*8, (wc*64 + 16 + lr)*40 + lg*8,
                       (wc*64 + 32 + lr)*40 + lg*8, (wc*64 + 48 + lr)*40 + lg*8 };
  const size_t agbase = (size_t)(r0 + srow)*K + spos;
  const size_t bgbase = (size_t)(c0 + srow)*K + spos;
  const int sl = srow*40 + spos;
#pragma unroll
  for (int k0 = 0; k0 < K; k0 += 32){
    *(short8v*)&As[sl]     = ld8(A + agbase + k0);
    *(short8v*)&As[sl + 8] = ld8(A + agbase + k0 + 8);
    *(short8v*)&Bs[sl]     = ld8(B + bgbase + k0);
    *(short8v*)&Bs[sl + 8] = ld8(B + bgbase + k0 + 8);
    if (SA){
      *(short8v*)&Asl[sl]     = ld8(Al + agbase + k0);
      *(short8v*)&Asl[sl + 8] = ld8(Al + agbase + k0 + 8);
    }
    if (SB){
      *(short8v*)&Bsl[sl]     = ld8(Bl + bgbase + k0);
      *(short8v*)&Bsl[sl + 8] = ld8(Bl + bgbase + k0 + 8);
    }
    __syncthreads();
    short8v af[4], bfr[4], afl[4], bfl[4];
#pragma unroll
    for (int f=0; f<4; f++){
      af[f]  = *(const short8v*)&As[ard[f]];
      bfr[f] = *(const short8v*)&Bs[brd[f]];
      if (SA) afl[f] = *(const short8v*)&Asl[ard[f]];
      if (SB) bfl[f] = *(const short8v*)&Bsl[brd[f]];
    }
#pragma unroll
    for (int fm=0; fm<4; fm++)
#pragma unroll
      for (int fn=0; fn<4; fn++){
        acc[fm][fn] = __builtin_amdgcn_mfma_f32_16x16x32_bf16(af[fm], bfr[fn], acc[fm][fn], 0,0,0);
        if (SB) acc[fm][fn] = __builtin_amdgcn_mfma_f32_16x16x32_bf16(af[fm], bfl[fn], acc[fm][fn], 0,0,0);
        if (SA) acc[fm][fn] = __builtin_amdgcn_mfma_f32_16x16x32_bf16(afl[fm], bfr[fn], acc[fm][fn], 0,0,0);
      }
    __syncthreads();
  }
  if (LNM == 0){
    float asv[4], adv[4];
    float rs[4][4], rd[4][4];
    if (ALS){
#pragma unroll
      for (int fn=0; fn<4; fn++){
        const int col = c0 + wc*64 + fn*16 + lr;
        asv[fn] = as_p[col]; adv[fn] = ad_p[col];
      }
#pragma unroll
      for (int fm=0; fm<4; fm++)
#pragma unroll
        for (int r=0; r<4; r++){ rs[fm][r] = 0.f; rd[fm][r] = 0.f; }
    }
#pragma unroll
    for (int fm=0; fm<4; fm++){
#pragma unroll
      for (int fn=0; fn<4; fn++){
        const int col = c0 + wc*64 + fn*16 + lr;
        const float bv = bias ? bias[col] : 0.f;
#pragma unroll
        for (int r=0; r<4; r++){
          const int row = r0 + wr*64 + fm*16 + lg*4 + r;
          float v = acc[fm][fn][r] + bv;
          if (ACT==1) v = fmaxf(v, 0.f);
          const size_t idx = (size_t)row*N + col;
          if (OMODE==0) Cf[idx] = v;
          else if (OMODE==1){
            bf16 bvv = __float2bfloat16(v);
            Ch[idx] = bvv;
            if (ALS){
              const float hv = __bfloat162float(bvv);
              rs[fm][r] += hv*asv[fn];
              rd[fm][r] += hv*adv[fn];
            }
          }
          else split_store(Ch, Cl, idx, v);
        }
      }
    }
    if (ALS){
      float* rb = (float*)As;
#pragma unroll
      for (int fm=0; fm<4; fm++)
#pragma unroll
        for (int r=0; r<4; r++){
          float s = rs[fm][r], dd = rd[fm][r];
#pragma unroll
          for (int mask=1; mask<16; mask<<=1){
            s  += __shfl_xor(s,  mask);
            dd += __shfl_xor(dd, mask);
          }
          rs[fm][r] = s; rd[fm][r] = dd;
        }
      if (wc == 1 && lr == 0){
#pragma unroll
        for (int fm=0; fm<4; fm++)
#pragma unroll
          for (int r=0; r<4; r++){
            const int row = wr*64 + fm*16 + lg*4 + r;
            rb[row] = rs[fm][r]; rb[128+row] = rd[fm][r];
          }
      }
      __syncthreads();
      if (wc == 0 && lr == 0){
        const int head = blockIdx.y;
#pragma unroll
        for (int fm=0; fm<4; fm++)
#pragma unroll
          for (int r=0; r<4; r++){
            const int row = wr*64 + fm*16 + lg*4 + r;
            als_p[(size_t)(r0+row)*4 + head] = rs[fm][r] + rb[row];
            ald_p[(size_t)(r0+row)*4 + head] = rd[fm][r] + rb[128+row];
          }
      }
    }
  } else {
    // ---- fused LayerNorm epilogue (N==128, full rows per block) ----
    float s1[4][4], s2[4][4];
#pragma unroll
    for (int fm=0; fm<4; fm++)
#pragma unroll
      for (int r=0; r<4; r++){ s1[fm][r] = 0.f; s2[fm][r] = 0.f; }
#pragma unroll
    for (int fm=0; fm<4; fm++)
#pragma unroll
      for (int fn=0; fn<4; fn++){
        const int col = wc*64 + fn*16 + lr;
        const float bv = bias[col];
#pragma unroll
        for (int r=0; r<4; r++){
          const int row = r0 + wr*64 + fm*16 + lg*4 + r;
          float xx = qbuf[(size_t)row*128 + col] + acc[fm][fn][r] + bv;
          acc[fm][fn][r] = xx;
          s1[fm][r] += xx;
          s2[fm][r] += xx*xx;
        }
      }
    float* rb = (float*)As;   // [128][2][2] -> row*4 + wc*2 + {0,1}
#pragma unroll
    for (int fm=0; fm<4; fm++)
#pragma unroll
      for (int r=0; r<4; r++){
        float a = s1[fm][r], b = s2[fm][r];
#pragma unroll
        for (int mask=1; mask<16; mask<<=1){
          a += __shfl_xor(a, mask);
          b += __shfl_xor(b, mask);
        }
        s1[fm][r] = a; s2[fm][r] = b;
      }
    if (lr == 0){
#pragma unroll
      for (int fm=0; fm<4; fm++)
#pragma unroll
        for (int r=0; r<4; r++){
          const int row = wr*64 + fm*16 + lg*4 + r;
          rb[row*4 + wc*2 + 0] = s1[fm][r];
          rb[row*4 + wc*2 + 1] = s2[fm][r];
        }
    }
    __syncthreads();
    float mu[4][4], ri[4][4];
#pragma unroll
    for (int fm=0; fm<4; fm++)
#pragma unroll
      for (int r=0; r<4; r++){
        const int row = wr*64 + fm*16 + lg*4 + r;
        const float st  = s1[fm][r] + rb[row*4 + (wc^1)*2 + 0];
        const float s2t = s2[fm][r] + rb[row*4 + (wc^1)*2 + 1];
        const float m  = st*(1.f/128.f);
        const float va = s2t*(1.f/128.f) - m*m;
        mu[fm][r] = m;
        ri[fm][r] = 1.f/sqrtf(va + 1e-5f);
      }
    if (LNM == 1){
#pragma unroll
      for (int fm=0; fm<4; fm++)
#pragma unroll
        for (int fn=0; fn<4; fn++){
          const int col = wc*64 + fn*16 + lr;
          const float gv = lng[col], bbv = lnb[col];
#pragma unroll
          for (int r=0; r<4; r++){
            const int row = r0 + wr*64 + fm*16 + lg*4 + r;
            const float ln = (acc[fm][fn][r] - mu[fm][r])*ri[fm][r]*gv + bbv;
            const size_t idx = (size_t)row*128 + col;
            y1f[idx] = ln;
            split_store(y1ho, y1lo, idx, ln);
          }
        }
    } else {
      float p0[4][4], p1[4][4];
#pragma unroll
      for (int fm=0; fm<4; fm++)
#pragma unroll
        for (int r=0; r<4; r++){ p0[fm][r] = 0.f; p1[fm][r] = 0.f; }
#pragma unroll
      for (int fm=0; fm<4; fm++)
#pragma unroll
        for (int fn=0; fn<4; fn++){
          const int col = wc*64 + fn*16 + lr;
          const float gv = lng[col], bbv = lnb[col];
          const float w0 = wcp[col*2], w1 = wcp[col*2+1];
#pragma unroll
          for (int r=0; r<4; r++){
            const float ln = (acc[fm][fn][r] - mu[fm][r])*ri[fm][r]*gv + bbv;
            p0[fm][r] += ln*w0;
            p1[fm][r] += ln*w1;
          }
        }
      __syncthreads();   // rb reuse
#pragma unroll
      for (int fm=0; fm<4; fm++)
#pragma unroll
        for (int r=0; r<4; r++){
          float a = p0[fm][r], b = p1[fm][r];
#pragma unroll
          for (int mask=1; mask<16; mask<<=1){
            a += __shfl_xor(a, mask);
            b += __shfl_xor(b, mask);
          }
          p0[fm][r] = a; p1[fm][r] = b;
        }
      if (lr == 0){
#pragma unroll
        for (int fm=0; fm<4; fm++)
#pragma unroll
          for (int r=0; r<4; r++){
            const int row = wr*64 + fm*16 + lg*4 + r;
            rb[row*4 + wc*2 + 0] = p0[fm][r];
            rb[row*4 + wc*2 + 1] = p1[fm][r];
          }
      }
      __syncthreads();
      if (wc == 0 && lr == 0){
#pragma unroll
        for (int fm=0; fm<4; fm++)
#pragma unroll
          for (int r=0; r<4; r++){
            const int row = wr*64 + fm*16 + lg*4 + r;
            outp[(size_t)(r0+row)*2 + 0] = p0[fm][r] + rb[row*4 + 2] + bcp[0];
            outp[(size_t)(r0+row)*2 + 1] = p1[fm][r] + rb[row*4 + 3] + bcp[1];
          }
      }
    }
  }
}

// ---------------- fused GAT aggregation (r18-measured + and/shl unpack) ----------------
template<bool CONCAT>
__global__ __launch_bounds__(256) void gat_fused_kernel(const bf16* __restrict__ hfeat,
    const float* __restrict__ als, const float* __restrict__ ald,
    const int* __restrict__ offs, const unsigned short* __restrict__ csr,
    const float* __restrict__ bias, void* __restrict__ outv,
    bf16* __restrict__ qh, bf16* __restrict__ ql){
  const int w = threadIdx.x >> 6, l = threadIdx.x & 63, g = l >> 4, s16 = l & 15;
  const int nb = blockIdx.x;
  const int n = (nb & 7)*2048 + (nb >> 3)*4 + w;   // cluster-contiguous, XCD-aligned
  const float adg = ald[(size_t)n*4 + g];
  const int beg = offs[n];
  const int cnt = offs[n+1] - beg + 1;             // + implicit self-loop (edge cnt-1)
  float ev[6]; int sv[6];
#pragma unroll
  for (int p=0;p<6;p++){
    const int i = s16 + p*16;
    int src = n;
    float e = -1e30f;
    if (i < cnt){
      if (i < cnt-1) src = (int)csr[beg+i];
      float t = als[(size_t)src*4+g] + adg;
      e = fmaxf(t, 0.2f*t);                        // leaky_relu 0.2
    }
    ev[p] = e; sv[p] = src;
  }
  float m = -1e30f;
#pragma unroll
  for (int p=0;p<6;p++) m = fmaxf(m, ev[p]);
  float den = 0.f;
#pragma unroll
  for (int p=0;p<6;p++) den += (ev[p] > -1e29f) ? __expf(ev[p]-m) : 0.f;
#pragma unroll
  for (int mask=1; mask<16; mask<<=1){
    float mo = __shfl_xor(m, mask);
    float dd = __shfl_xor(den, mask);
    float nm = fmaxf(m, mo);
    den = den*__expf(m-nm) + dd*__expf(mo-nm);
    m = nm;
  }
  const float C = __expf(-m)/(den + 1e-16f);
  int pk[6];
#pragma unroll
  for (int p=0;p<6;p++){
    float a = (ev[p] > -1e29f) ? __expf(ev[p])*C : 0.f;
    bf16 ab = __float2bfloat16(a);
    pk[p] = ((int)*(unsigned short*)&ab << 16) | (sv[p] & 0xFFFF);
  }
  float acc[8] = {0,0,0,0,0,0,0,0};
  const int fb = l*8;
  const bf16* hp = hfeat + fb;
#pragma unroll
  for (int p=0;p<6;p++){
    const int pbase = p*16;
    if (pbase < cnt){
      const int lim = (cnt - pbase < 16) ? (cnt - pbase) : 16;
      int u_c = __shfl(pk[p], (l & 48));
      uint4v hv_c = *(const uint4v*)(const void*)(hp + (size_t)(u_c & 0xFFFF)*FEAT);
      for (int j=1; j<lim; ++j){
        const int u_n = __shfl(pk[p], (l & 48) | j);
        const uint4v hv_n = *(const uint4v*)(const void*)(hp + (size_t)(u_n & 0xFFFF)*FEAT);
        const float a_c = __uint_as_float((unsigned)u_c & 0xFFFF0000u);
#pragma unroll
        for (int k=0;k<4;k++){
          acc[2*k]   += a_c * __uint_as_float(hv_c[k] << 16);
          acc[2*k+1] += a_c * __uint_as_float(hv_c[k] & 0xFFFF0000u);
        }
        u_c = u_n; hv_c = hv_n;
      }
      const float a_c = __uint_as_float((unsigned)u_c & 0xFFFF0000u);
#pragma unroll
      for (int k=0;k<4;k++){
        acc[2*k]   += a_c * __uint_as_float(hv_c[k] << 16);
        acc[2*k+1] += a_c * __uint_as_float(hv_c[k] & 0xFFFF0000u);
      }
    }
  }
  for (int i = 96; i < cnt; ++i){
    const int src = (i < cnt-1) ? (int)csr[beg+i] : n;
    float t = als[(size_t)src*4+g] + adg;
    t = fmaxf(t, 0.2f*t);
    const float a = __expf(t)*C;
    const short8v hv = *(const short8v*)(const void*)&hfeat[(size_t)src*FEAT + fb];
#pragma unroll
    for (int k=0;k<8;k++) acc[k] += a * b2f(hv[k]);
  }
  if (CONCAT){
    short8v ov;
#pragma unroll
    for (int j=0;j<8;j++){
      float v = acc[j] + bias[fb+j];
      v = v > 0.f ? v : expm1f(v);               // fused ELU
      bf16 bv = __float2bfloat16(v);
      ov[j] = (short)*(unsigned short*)&bv;
    }
    *(short8v*)((char*)outv + ((size_t)n*FEAT + fb)*2) = ov;
  } else {
#pragma unroll
    for (int j=0;j<8;j++){
      acc[j] += __shfl_xor(acc[j], 16);
      acc[j] += __shfl_xor(acc[j], 32);
    }
    if (l < 16){
      float* op = (float*)outv + (size_t)n*128 + l*8;
#pragma unroll
      for (int j=0;j<8;j++){
        const int col = l*8 + j;
        float v = 0.25f*acc[j] + bias[col];
        float ex = __expf((float)(col & ~1) * (-9.210340371976184f/128.f));
        float pe = (col & 1) ? cosf(4.f*ex) : sinf(4.f*ex);
        float q = v + pe;
        op[j] = q;
        split_store(qh, ql, (size_t)n*128 + col, q);
      }
    }
  }
}

extern "C" void kernel_launch(void* const* d_in, const int* in_sizes, int n_in,
                              void* d_out, int out_size, void* d_ws, size_t ws_size,
                              hipStream_t stream){
  const float* x      = (const float*)d_in[0];
  const int*   ei     = (const int*)d_in[1];
  const float* W1     = (const float*)d_in[3];
  const float* a_src1 = (const float*)d_in[4];
  const float* a_dst1 = (const float*)d_in[5];
  const float* b1     = (const float*)d_in[6];
  const float* W2     = (const float*)d_in[7];
  const float* a_src2 = (const float*)d_in[8];
  const float* a_dst2 = (const float*)d_in[9];
  const float* b2     = (const float*)d_in[10];
  const float* wv     = (const float*)d_in[15];
  const float* bv     = (const float*)d_in[16];
  const float* wo     = (const float*)d_in[17];
  const float* bo     = (const float*)d_in[18];
  const float* ln_g   = (const float*)d_in[19];
  const float* ln_b   = (const float*)d_in[20];
  const float* f1     = (const float*)d_in[21];
  const float* fb1    = (const float*)d_in[22];
  const float* f2     = (const float*)d_in[23];
  const float* fb2    = (const float*)d_in[24];
  const float* wc     = (const float*)d_in[25];
  const float* bc     = (const float*)d_in[26];
  float* outp = (float*)d_out;

  const int E = in_sizes[1] / 2;
  const int n = NODES;
  const int tE = 2*E;
  const size_t MB = 1024*1024;

  const size_t NEED = 36*MB;
  if (ws_size < NEED){
    sentinel_kernel<<<(out_size+255)/256, 256, 0, stream>>>(outp, out_size,
        1000.0f + (float)(ws_size / MB));
    return;
  }

  // ---- arena [0,36) MB ----
  char* base = (char*)d_ws;
  int* counts = (int*)(base + 0);
  int* cursor = (int*)(base + 65536);
  bf16*  h1    = (bf16*)(base + 0);          // [0,16)
  bf16*  xh    = (bf16*)(base + 16*MB);      // [16,20)
  bf16*  h     = (bf16*)(base + 16*MB);      // [16,32)
  bf16*  h2f   = (bf16*)(base + 0);          // [0,16)
  float* h2q   = (float*)(base + 16*MB);     // [16,24)
  bf16*  qh    = (bf16*)(base + 24*MB);      // [24,28)
  bf16*  ql    = (bf16*)(base + 28*MB);      // [28,32)
  bf16*  vh    = (bf16*)(base + 0);          // [0,4)
  bf16*  vl    = (bf16*)(base + 4*MB);       // [4,8)
  float* y1    = (float*)(base + 24*MB);     // [24,32)  (qh/ql dead after wv)
  bf16*  y1h   = (bf16*)(base + 0);          // [0,4)    (row-aligned in-place vs vh: safe)
  bf16*  y1l   = (bf16*)(base + 4*MB);       // [4,8)
  bf16*  hidden= (bf16*)(base + 8*MB);       // [8,24)
  char* u = base + 32*MB;
  bf16* w1h = (bf16*)u; u += 131072;
  bf16* w2h = (bf16*)u; u += 524288;
  bf16* wvh = (bf16*)u; u += 32768;   bf16* wvl = (bf16*)u; u += 32768;
  bf16* woh = (bf16*)u; u += 32768;   bf16* wol = (bf16*)u; u += 32768;
  bf16* f1h = (bf16*)u; u += 131072;  bf16* f1l = (bf16*)u; u += 131072;
  bf16* f2h = (bf16*)u; u += 131072;  bf16* f2l = (bf16*)u; u += 131072;
  float* als  = (float*)u; u += (size_t)n*4*4;
  float* ald  = (float*)u; u += (size_t)n*4*4;
  int* offs   = (int*)u;   u += (size_t)(n+1)*4 + 252;
  unsigned short* csr = (unsigned short*)u; u += (size_t)tE*2;

  // ---- prep + CSR ----
  PrepArgs P = { x,W1,W2,wv,wo,f1,f2, xh,w1h,w2h,wvh,wvl,woh,wol,f1h,f1l,f2h,f2l };
  prep_kernel<<<632, 256, 0, stream>>>(P);
  zero_kernel<<<(n+255)/256, 256, 0, stream>>>(counts, n);
  count_kernel<<<(tE+255)/256, 256, 0, stream>>>(ei, counts, E);
  scan_kernel<<<1, 1024, 0, stream>>>(counts, offs, cursor);
  fill_kernel<<<(tE+255)/256, 256, 0, stream>>>(ei, cursor, csr, E);

  // ---- GAT layer 1 (als/ald fused) ----
  lgemm<128,0,0,0,1,1,0><<<dim3(128,4), 256, 0, stream>>>(xh, nullptr, w1h, nullptr, nullptr,
      nullptr, h1, nullptr, 512, a_src1, a_dst1, als, ald,
      nullptr,nullptr,nullptr,nullptr,nullptr,nullptr,nullptr,nullptr,nullptr);
  gat_fused_kernel<true><<<n/4, 256, 0, stream>>>(h1, als, ald, offs, csr, b1, h, nullptr, nullptr);

  // ---- GAT layer 2 (als/ald fused) ----
  lgemm<512,0,0,0,1,1,0><<<dim3(128,4), 256, 0, stream>>>(h, nullptr, w2h, nullptr, nullptr,
      nullptr, h2f, nullptr, 512, a_src2, a_dst2, als, ald,
      nullptr,nullptr,nullptr,nullptr,nullptr,nullptr,nullptr,nullptr,nullptr);
  gat_fused_kernel<false><<<n/4, 256, 0, stream>>>(h2f, als, ald, offs, csr, b2, h2q, qh, ql);

  // ---- temporal attention tail: wv -> wo(+LN1) -> ffn1 -> ffn2(+LN2+head) ----
  lgemm<128,1,1,0,2,0,0><<<dim3(128,1), 256, 0, stream>>>(qh, ql, wvh, wvl, bv,
      nullptr, vh, vl, 128, nullptr, nullptr, nullptr, nullptr,
      nullptr,nullptr,nullptr,nullptr,nullptr,nullptr,nullptr,nullptr,nullptr);
  lgemm<128,1,1,0,0,0,1><<<dim3(128,1), 256, 0, stream>>>(vh, vl, woh, wol, bo,
      nullptr, nullptr, nullptr, 128, nullptr, nullptr, nullptr, nullptr,
      h2q, ln_g, ln_b, y1, y1h, y1l, nullptr, nullptr, nullptr);
  lgemm<128,1,1,1,1,0,0><<<dim3(128,4), 256, 0, stream>>>(y1h, y1l, f1h, f1l, fb1,
      nullptr, hidden, nullptr, 512, nullptr, nullptr, nullptr, nullptr,
      nullptr,nullptr,nullptr,nullptr,nullptr,nullptr,nullptr,nullptr,nullptr);
  lgemm<512,0,1,0,0,0,2><<<dim3(128,1), 256, 0, stream>>>(hidden, nullptr, f2h, f2l, fb2,
      nullptr, nullptr, nullptr, 128, nullptr, nullptr, nullptr, nullptr,
      y1, ln_g, ln_b, nullptr, nullptr, nullptr, wc, bc, outp);
}

// Round 23
// 250.059 us; speedup vs baseline: 1.2149x; 1.0114x over previous
//
#include <hip/hip_runtime.h>
#include <hip/hip_bf16.h>

#define NODES 16384
#define FEAT 512
typedef __hip_bfloat16 bf16;
typedef __hip_bfloat162 bf162;
typedef short short8v __attribute__((ext_vector_type(8)));
typedef unsigned int uint4v __attribute__((ext_vector_type(4)));
typedef float f32x4 __attribute__((ext_vector_type(4)));

static __device__ __forceinline__ float b2f(short s){
  return __uint_as_float(((unsigned)(unsigned short)s) << 16);
}
static __device__ __forceinline__ void split_store(bf16* h, bf16* l, size_t i, float v){
  bf16 hi = __float2bfloat16(v);
  h[i] = hi; l[i] = __float2bfloat16(v - __bfloat162float(hi));
}

// ---------------- diagnostic sentinel ----------------
__global__ void sentinel_kernel(float* __restrict__ out, int n, float v){
  int i = blockIdx.x*blockDim.x + threadIdx.x;
  if (i < n) out[i] = v;
}

// ---------------- CSR build ----------------
__global__ void zero_kernel(int* __restrict__ p, int n){
  int i = blockIdx.x*blockDim.x + threadIdx.x;
  if (i < n) p[i] = 0;
}
__global__ void count_kernel(const int* __restrict__ ei, int* __restrict__ counts, int E){
  int i = blockIdx.x*blockDim.x + threadIdx.x;
  if (i < 2*E){
    int dst = (i < E) ? ei[E+i] : ei[i-E];
    atomicAdd(&counts[dst], 1);
  }
}
__global__ __launch_bounds__(1024) void scan_kernel(const int* __restrict__ counts,
                                                    int* __restrict__ offs, int* __restrict__ cursor){
  __shared__ int sh[1024];
  const int t = threadIdx.x;
  int loc[16]; int s = 0;
#pragma unroll
  for (int i=0;i<16;i++){ loc[i] = counts[t*16+i]; s += loc[i]; }
  sh[t] = s; __syncthreads();
  for (int d=1; d<1024; d<<=1){
    int v = (t>=d) ? sh[t-d] : 0;
    __syncthreads(); sh[t] += v; __syncthreads();
  }
  int run = (t==0) ? 0 : sh[t-1];
#pragma unroll
  for (int i=0;i<16;i++){ offs[t*16+i] = run; cursor[t*16+i] = run; run += loc[i]; }
  if (t==1023) offs[NODES] = run;
}
__global__ void fill_kernel(const int* __restrict__ ei, int* __restrict__ cursor,
                            unsigned short* __restrict__ csr, int E){
  int i = blockIdx.x*blockDim.x + threadIdx.x;
  if (i < 2*E){
    int src = ei[i];
    int dst = (i < E) ? ei[E+i] : ei[i-E];
    int pos = atomicAdd(&cursor[dst], 1);
    csr[pos] = (unsigned short)src;
  }
}

// ---------------- prep: x cast + LDS-tiled transpose-cast of all weights ----------------
struct PrepArgs {
  const float *x,*W1,*W2,*wv,*wo,*f1,*f2;
  bf16 *xh,*w1h,*w2h,*wvh,*wvl,*woh,*wol,*f1h,*f1l,*f2h,*f2l;
};
__global__ __launch_bounds__(256) void prep_kernel(PrepArgs P){
  const int b = blockIdx.x;
  const int t = threadIdx.x;
  if (b < 512){
    const size_t base = (size_t)b*4096;
#pragma unroll
    for (int k=0;k<16;k++){
      const size_t i = base + t + 256*k;
      P.xh[i] = __float2bfloat16(P.x[i]);
    }
    return;
  }
  __shared__ float tile[64][65];
  const float* src; bf16 *dh; bf16 *dl; int R, C, ti;
  int bb = b - 512;
  if (bb < 16){ src=P.W1; dh=P.w1h; dl=nullptr; R=128; C=512; ti=bb; }
  else if ((bb-=16) < 64){ src=P.W2; dh=P.w2h; dl=nullptr; R=512; C=512; ti=bb; }
  else if ((bb-=64) < 4){ src=P.wv; dh=P.wvh; dl=P.wvl; R=128; C=128; ti=bb; }
  else if ((bb-=4) < 4){ src=P.wo; dh=P.woh; dl=P.wol; R=128; C=128; ti=bb; }
  else if ((bb-=4) < 16){ src=P.f1; dh=P.f1h; dl=P.f1l; R=128; C=512; ti=bb; }
  else { bb-=16; src=P.f2; dh=P.f2h; dl=P.f2l; R=512; C=128; ti=bb; }
  const int ctiles = C/64;
  const int r0 = (ti/ctiles)*64, c0 = (ti%ctiles)*64;
  const int r = t >> 6, c = t & 63;
#pragma unroll
  for (int i=0;i<16;i++)
    tile[r + 4*i][c] = src[(size_t)(r0 + r + 4*i)*C + c0 + c];
  __syncthreads();
#pragma unroll
  for (int i=0;i<16;i++){
    const int oc   = c0 + r + 4*i;
    const int orow = r0 + c;
    const float v = tile[c][r + 4*i];
    const size_t oi = (size_t)oc*R + orow;
    if (dl){ split_store(dh, dl, oi, v); } else { dh[oi] = __float2bfloat16(v); }
  }
}

static __device__ __forceinline__ short8v ld8(const bf16* p){
  return *(const short8v*)(const void*)(p);
}

// ---------------- LDS-staged MFMA GEMM: 128x128 tile, 4 waves ----------------
// ALS=1: fused per-(row,head) attention dots. LNM=2: fused LN + classifier head.
template<int K, int SA, int SB, int ACT, int OMODE, int ALS, int LNM>
__global__ __launch_bounds__(256) void lgemm(
    const bf16* __restrict__ A, const bf16* __restrict__ Al,
    const bf16* __restrict__ B, const bf16* __restrict__ Bl,
    const float* __restrict__ bias,
    float* __restrict__ Cf, bf16* __restrict__ Ch, bf16* __restrict__ Cl, int N,
    const float* __restrict__ as_p, const float* __restrict__ ad_p,
    float* __restrict__ als_p, float* __restrict__ ald_p,
    const float* __restrict__ qbuf, const float* __restrict__ lng, const float* __restrict__ lnb,
    float* __restrict__ y1f, bf16* __restrict__ y1ho, bf16* __restrict__ y1lo,
    const float* __restrict__ wcp, const float* __restrict__ bcp, float* __restrict__ outp){
  __shared__ bf16 As[128*40];
  __shared__ bf16 Bs[128*40];
  __shared__ bf16 Asl[SA ? 128*40 : 1];
  __shared__ bf16 Bsl[SB ? 128*40 : 1];
  const int tid = threadIdx.x;
  const int l = tid & 63, w = tid >> 6;
  const int lg = l >> 4, lr = l & 15;
  const int wr = w >> 1, wc = w & 1;
  const int r0 = blockIdx.x*128;
  const int c0 = blockIdx.y*128;
  const int srow = tid >> 1;
  const int spos = (tid & 1) * 16;
  f32x4 acc[4][4] = {};
  const int ard[4] = { (wr*64 +  0 + lr)*40 + lg*8, (wr*64 + 16 + lr)*40 + lg*8,
                       (wr*64 + 32 + lr)*40 + lg*8, (wr*64 + 48 + lr)*40 + lg*8 };
  const int brd[4] = { (wc*64 +  0 + lr)*40 + lg*8, (wc*64 + 16 + lr)*40 + lg*8,
                       (wc*64 + 32 + lr)*40 + lg*8, (wc*64 + 48 + lr)*40 + lg*8 };
  const size_t agbase = (size_t)(r0 + srow)*K + spos;
  const size_t bgbase = (size_t)(c0 + srow)*K + spos;
  const int sl = srow*40 + spos;
#pragma unroll
  for (int k0 = 0; k0 < K; k0 += 32){
    *(short8v*)&As[sl]     = ld8(A + agbase + k0);
    *(short8v*)&As[sl + 8] = ld8(A + agbase + k0 + 8);
    *(short8v*)&Bs[sl]     = ld8(B + bgbase + k0);
    *(short8v*)&Bs[sl + 8] = ld8(B + bgbase + k0 + 8);
    if (SA){
      *(short8v*)&Asl[sl]     = ld8(Al + agbase + k0);
      *(short8v*)&Asl[sl + 8] = ld8(Al + agbase + k0 + 8);
    }
    if (SB){
      *(short8v*)&Bsl[sl]     = ld8(Bl + bgbase + k0);
      *(short8v*)&Bsl[sl + 8] = ld8(Bl + bgbase + k0 + 8);
    }
    __syncthreads();
    short8v af[4], bfr[4], afl[4], bfl[4];
#pragma unroll
    for (int f=0; f<4; f++){
      af[f]  = *(const short8v*)&As[ard[f]];
      bfr[f] = *(const short8v*)&Bs[brd[f]];
      if (SA) afl[f] = *(const short8v*)&Asl[ard[f]];
      if (SB) bfl[f] = *(const short8v*)&Bsl[brd[f]];
    }
#pragma unroll
    for (int fm=0; fm<4; fm++)
#pragma unroll
      for (int fn=0; fn<4; fn++){
        acc[fm][fn] = __builtin_amdgcn_mfma_f32_16x16x32_bf16(af[fm], bfr[fn], acc[fm][fn], 0,0,0);
        if (SB) acc[fm][fn] = __builtin_amdgcn_mfma_f32_16x16x32_bf16(af[fm], bfl[fn], acc[fm][fn], 0,0,0);
        if (SA) acc[fm][fn] = __builtin_amdgcn_mfma_f32_16x16x32_bf16(afl[fm], bfr[fn], acc[fm][fn], 0,0,0);
      }
    __syncthreads();
  }
  if (LNM == 0){
    float asv[4], adv[4];
    float rs[4][4], rd[4][4];
    if (ALS){
#pragma unroll
      for (int fn=0; fn<4; fn++){
        const int col = c0 + wc*64 + fn*16 + lr;
        asv[fn] = as_p[col]; adv[fn] = ad_p[col];
      }
#pragma unroll
      for (int fm=0; fm<4; fm++)
#pragma unroll
        for (int r=0; r<4; r++){ rs[fm][r] = 0.f; rd[fm][r] = 0.f; }
    }
#pragma unroll
    for (int fm=0; fm<4; fm++){
#pragma unroll
      for (int fn=0; fn<4; fn++){
        const int col = c0 + wc*64 + fn*16 + lr;
        const float bv = bias ? bias[col] : 0.f;
#pragma unroll
        for (int r=0; r<4; r++){
          const int row = r0 + wr*64 + fm*16 + lg*4 + r;
          float v = acc[fm][fn][r] + bv;
          if (ACT==1) v = fmaxf(v, 0.f);
          const size_t idx = (size_t)row*N + col;
          if (OMODE==0) Cf[idx] = v;
          else if (OMODE==1){
            bf16 bvv = __float2bfloat16(v);
            Ch[idx] = bvv;
            if (ALS){
              const float hv = __bfloat162float(bvv);
              rs[fm][r] += hv*asv[fn];
              rd[fm][r] += hv*adv[fn];
            }
          }
          else split_store(Ch, Cl, idx, v);
        }
      }
    }
    if (ALS){
      float* rb = (float*)As;
#pragma unroll
      for (int fm=0; fm<4; fm++)
#pragma unroll
        for (int r=0; r<4; r++){
          float s = rs[fm][r], dd = rd[fm][r];
#pragma unroll
          for (int mask=1; mask<16; mask<<=1){
            s  += __shfl_xor(s,  mask);
            dd += __shfl_xor(dd, mask);
          }
          rs[fm][r] = s; rd[fm][r] = dd;
        }
      if (wc == 1 && lr == 0){
#pragma unroll
        for (int fm=0; fm<4; fm++)
#pragma unroll
          for (int r=0; r<4; r++){
            const int row = wr*64 + fm*16 + lg*4 + r;
            rb[row] = rs[fm][r]; rb[128+row] = rd[fm][r];
          }
      }
      __syncthreads();
      if (wc == 0 && lr == 0){
        const int head = blockIdx.y;
#pragma unroll
        for (int fm=0; fm<4; fm++)
#pragma unroll
          for (int r=0; r<4; r++){
            const int row = wr*64 + fm*16 + lg*4 + r;
            als_p[(size_t)(r0+row)*4 + head] = rs[fm][r] + rb[row];
            ald_p[(size_t)(r0+row)*4 + head] = rd[fm][r] + rb[128+row];
          }
      }
    }
  } else {
    // ---- fused LayerNorm + classifier head (LNM==2; N==128 full rows) ----
    float s1[4][4], s2[4][4];
#pragma unroll
    for (int fm=0; fm<4; fm++)
#pragma unroll
      for (int r=0; r<4; r++){ s1[fm][r] = 0.f; s2[fm][r] = 0.f; }
#pragma unroll
    for (int fm=0; fm<4; fm++)
#pragma unroll
      for (int fn=0; fn<4; fn++){
        const int col = wc*64 + fn*16 + lr;
        const float bv = bias[col];
#pragma unroll
        for (int r=0; r<4; r++){
          const int row = r0 + wr*64 + fm*16 + lg*4 + r;
          float xx = qbuf[(size_t)row*128 + col] + acc[fm][fn][r] + bv;
          acc[fm][fn][r] = xx;
          s1[fm][r] += xx;
          s2[fm][r] += xx*xx;
        }
      }
    float* rb = (float*)As;
#pragma unroll
    for (int fm=0; fm<4; fm++)
#pragma unroll
      for (int r=0; r<4; r++){
        float a = s1[fm][r], b = s2[fm][r];
#pragma unroll
        for (int mask=1; mask<16; mask<<=1){
          a += __shfl_xor(a, mask);
          b += __shfl_xor(b, mask);
        }
        s1[fm][r] = a; s2[fm][r] = b;
      }
    if (lr == 0){
#pragma unroll
      for (int fm=0; fm<4; fm++)
#pragma unroll
        for (int r=0; r<4; r++){
          const int row = wr*64 + fm*16 + lg*4 + r;
          rb[row*4 + wc*2 + 0] = s1[fm][r];
          rb[row*4 + wc*2 + 1] = s2[fm][r];
        }
    }
    __syncthreads();
    float mu[4][4], ri[4][4];
#pragma unroll
    for (int fm=0; fm<4; fm++)
#pragma unroll
      for (int r=0; r<4; r++){
        const int row = wr*64 + fm*16 + lg*4 + r;
        const float st  = s1[fm][r] + rb[row*4 + (wc^1)*2 + 0];
        const float s2t = s2[fm][r] + rb[row*4 + (wc^1)*2 + 1];
        const float m  = st*(1.f/128.f);
        const float va = s2t*(1.f/128.f) - m*m;
        mu[fm][r] = m;
        ri[fm][r] = 1.f/sqrtf(va + 1e-5f);
      }
    float p0[4][4], p1[4][4];
#pragma unroll
    for (int fm=0; fm<4; fm++)
#pragma unroll
      for (int r=0; r<4; r++){ p0[fm][r] = 0.f; p1[fm][r] = 0.f; }
#pragma unroll
    for (int fm=0; fm<4; fm++)
#pragma unroll
      for (int fn=0; fn<4; fn++){
        const int col = wc*64 + fn*16 + lr;
        const float gv = lng[col], bbv = lnb[col];
        const float w0 = wcp[col*2], w1 = wcp[col*2+1];
#pragma unroll
        for (int r=0; r<4; r++){
          const float ln = (acc[fm][fn][r] - mu[fm][r])*ri[fm][r]*gv + bbv;
          p0[fm][r] += ln*w0;
          p1[fm][r] += ln*w1;
        }
      }
    __syncthreads();
#pragma unroll
    for (int fm=0; fm<4; fm++)
#pragma unroll
      for (int r=0; r<4; r++){
        float a = p0[fm][r], b = p1[fm][r];
#pragma unroll
        for (int mask=1; mask<16; mask<<=1){
          a += __shfl_xor(a, mask);
          b += __shfl_xor(b, mask);
        }
        p0[fm][r] = a; p1[fm][r] = b;
      }
    if (lr == 0){
#pragma unroll
      for (int fm=0; fm<4; fm++)
#pragma unroll
        for (int r=0; r<4; r++){
          const int row = wr*64 + fm*16 + lg*4 + r;
          rb[row*4 + wc*2 + 0] = p0[fm][r];
          rb[row*4 + wc*2 + 1] = p1[fm][r];
        }
    }
    __syncthreads();
    if (wc == 0 && lr == 0){
#pragma unroll
      for (int fm=0; fm<4; fm++)
#pragma unroll
        for (int r=0; r<4; r++){
          const int row = wr*64 + fm*16 + lg*4 + r;
          outp[(size_t)(r0+row)*2 + 0] = p0[fm][r] + rb[row*4 + 2] + bcp[0];
          outp[(size_t)(r0+row)*2 + 1] = p1[fm][r] + rb[row*4 + 3] + bcp[1];
        }
    }
  }
}

// ---------------- chained attention tail: v=q@wv+bv -> ao=v@wo+bo -> LN1 ----------------
// v never leaves the CU: split to bf16 pair in-register (same rounding as split_store),
// staged through the reused LDS A-tile per 32-k block. MFMA order identical to the
// two-kernel version -> bit-identical y1.
__global__ __launch_bounds__(256) void attn_chain_kernel(
    const bf16* __restrict__ qh, const bf16* __restrict__ ql,
    const bf16* __restrict__ wvh, const bf16* __restrict__ wvl,
    const float* __restrict__ bv,
    const bf16* __restrict__ woh, const bf16* __restrict__ wol,
    const float* __restrict__ bo,
    const float* __restrict__ h2q, const float* __restrict__ lng, const float* __restrict__ lnb,
    float* __restrict__ y1f, bf16* __restrict__ y1ho, bf16* __restrict__ y1lo){
  __shared__ bf16 As[128*40];
  __shared__ bf16 Bs[128*40];
  __shared__ bf16 Asl[128*40];
  __shared__ bf16 Bsl[128*40];
  const int tid = threadIdx.x;
  const int l = tid & 63, w = tid >> 6;
  const int lg = l >> 4, lr = l & 15;
  const int wr = w >> 1, wc = w & 1;
  const int r0 = blockIdx.x*128;
  const int srow = tid >> 1;
  const int spos = (tid & 1) * 16;
  const int sl = srow*40 + spos;
  const int ard[4] = { (wr*64 +  0 + lr)*40 + lg*8, (wr*64 + 16 + lr)*40 + lg*8,
                       (wr*64 + 32 + lr)*40 + lg*8, (wr*64 + 48 + lr)*40 + lg*8 };
  const int brd[4] = { (wc*64 +  0 + lr)*40 + lg*8, (wc*64 + 16 + lr)*40 + lg*8,
                       (wc*64 + 32 + lr)*40 + lg*8, (wc*64 + 48 + lr)*40 + lg*8 };
  // ---- GEMM1: v = q @ wv  (SA=SB=1, K=128) ----
  f32x4 acc[4][4] = {};
  {
    const size_t ag = (size_t)(r0 + srow)*128 + spos;
    const size_t bg = (size_t)srow*128 + spos;
#pragma unroll
    for (int k0 = 0; k0 < 128; k0 += 32){
      *(short8v*)&As[sl]      = ld8(qh + ag + k0);
      *(short8v*)&As[sl + 8]  = ld8(qh + ag + k0 + 8);
      *(short8v*)&Asl[sl]     = ld8(ql + ag + k0);
      *(short8v*)&Asl[sl + 8] = ld8(ql + ag + k0 + 8);
      *(short8v*)&Bs[sl]      = ld8(wvh + bg + k0);
      *(short8v*)&Bs[sl + 8]  = ld8(wvh + bg + k0 + 8);
      *(short8v*)&Bsl[sl]     = ld8(wvl + bg + k0);
      *(short8v*)&Bsl[sl + 8] = ld8(wvl + bg + k0 + 8);
      __syncthreads();
      short8v af[4], bfr[4], afl[4], bfl[4];
#pragma unroll
      for (int f=0; f<4; f++){
        af[f]  = *(const short8v*)&As[ard[f]];
        bfr[f] = *(const short8v*)&Bs[brd[f]];
        afl[f] = *(const short8v*)&Asl[ard[f]];
        bfl[f] = *(const short8v*)&Bsl[brd[f]];
      }
#pragma unroll
      for (int fm=0; fm<4; fm++)
#pragma unroll
        for (int fn=0; fn<4; fn++){
          acc[fm][fn] = __builtin_amdgcn_mfma_f32_16x16x32_bf16(af[fm], bfr[fn], acc[fm][fn], 0,0,0);
          acc[fm][fn] = __builtin_amdgcn_mfma_f32_16x16x32_bf16(af[fm], bfl[fn], acc[fm][fn], 0,0,0);
          acc[fm][fn] = __builtin_amdgcn_mfma_f32_16x16x32_bf16(afl[fm], bfr[fn], acc[fm][fn], 0,0,0);
        }
      __syncthreads();
    }
  }
  // v value: acc + bv[col]; split in-register (identical rounding to split_store)
  // ---- GEMM2: ao = v @ wo, v staged through As/Asl per 32-k block ----
  f32x4 acc2[4][4] = {};
  {
    const size_t bg = (size_t)srow*128 + spos;
#pragma unroll
    for (int kb=0; kb<4; ++kb){
      // owning waves (wc == kb>>1) write their two fn-columns of v into As/Asl
      if (wc == (kb >> 1)){
        const int fnb = (kb & 1)*2;
#pragma unroll
        for (int fm=0; fm<4; fm++)
#pragma unroll
          for (int fi=0; fi<2; fi++){
            const int fn = fnb + fi;
            const int col = wc*64 + fn*16 + lr;
            const float bvv = bv[col];
            const int kk = col - kb*32;
#pragma unroll
            for (int r=0; r<4; r++){
              const int row = wr*64 + fm*16 + lg*4 + r;
              const float v = acc[fm][fn][r] + bvv;
              const bf16 hi = __float2bfloat16(v);
              const bf16 lo = __float2bfloat16(v - __bfloat162float(hi));
              As[row*40 + kk]  = hi;
              Asl[row*40 + kk] = lo;
            }
          }
      }
      *(short8v*)&Bs[sl]      = ld8(woh + bg + kb*32);
      *(short8v*)&Bs[sl + 8]  = ld8(woh + bg + kb*32 + 8);
      *(short8v*)&Bsl[sl]     = ld8(wol + bg + kb*32);
      *(short8v*)&Bsl[sl + 8] = ld8(wol + bg + kb*32 + 8);
      __syncthreads();
      short8v af[4], bfr[4], afl[4], bfl[4];
#pragma unroll
      for (int f=0; f<4; f++){
        af[f]  = *(const short8v*)&As[ard[f] - 0];      // k = lg*8 within this 32-k block
        bfr[f] = *(const short8v*)&Bs[brd[f]];
        afl[f] = *(const short8v*)&Asl[ard[f] - 0];
        bfl[f] = *(const short8v*)&Bsl[brd[f]];
      }
#pragma unroll
      for (int fm=0; fm<4; fm++)
#pragma unroll
        for (int fn=0; fn<4; fn++){
          acc2[fm][fn] = __builtin_amdgcn_mfma_f32_16x16x32_bf16(af[fm], bfr[fn], acc2[fm][fn], 0,0,0);
          acc2[fm][fn] = __builtin_amdgcn_mfma_f32_16x16x32_bf16(af[fm], bfl[fn], acc2[fm][fn], 0,0,0);
          acc2[fm][fn] = __builtin_amdgcn_mfma_f32_16x16x32_bf16(afl[fm], bfr[fn], acc2[fm][fn], 0,0,0);
        }
      __syncthreads();
    }
  }
  // ---- LN1 epilogue: y1 = LN(h2q + ao + bo) ----
  float s1[4][4], s2[4][4];
#pragma unroll
  for (int fm=0; fm<4; fm++)
#pragma unroll
    for (int r=0; r<4; r++){ s1[fm][r] = 0.f; s2[fm][r] = 0.f; }
#pragma unroll
  for (int fm=0; fm<4; fm++)
#pragma unroll
    for (int fn=0; fn<4; fn++){
      const int col = wc*64 + fn*16 + lr;
      const float bvv = bo[col];
#pragma unroll
      for (int r=0; r<4; r++){
        const int row = r0 + wr*64 + fm*16 + lg*4 + r;
        float xx = h2q[(size_t)row*128 + col] + acc2[fm][fn][r] + bvv;
        acc2[fm][fn][r] = xx;
        s1[fm][r] += xx;
        s2[fm][r] += xx*xx;
      }
    }
  float* rb = (float*)As;
#pragma unroll
  for (int fm=0; fm<4; fm++)
#pragma unroll
    for (int r=0; r<4; r++){
      float a = s1[fm][r], b = s2[fm][r];
#pragma unroll
      for (int mask=1; mask<16; mask<<=1){
        a += __shfl_xor(a, mask);
        b += __shfl_xor(b, mask);
      }
      s1[fm][r] = a; s2[fm][r] = b;
    }
  if (lr == 0){
#pragma unroll
    for (int fm=0; fm<4; fm++)
#pragma unroll
      for (int r=0; r<4; r++){
        const int row = wr*64 + fm*16 + lg*4 + r;
        rb[row*4 + wc*2 + 0] = s1[fm][r];
        rb[row*4 + wc*2 + 1] = s2[fm][r];
      }
  }
  __syncthreads();
#pragma unroll
  for (int fm=0; fm<4; fm++)
#pragma unroll
    for (int fn=0; fn<4; fn++){
      const int col = wc*64 + fn*16 + lr;
      const float gv = lng[col], bbv = lnb[col];
#pragma unroll
      for (int r=0; r<4; r++){
        const int row4 = wr*64 + fm*16 + lg*4 + r;
        const float st  = s1[fm][r] + rb[row4*4 + (wc^1)*2 + 0];
        const float s2t = s2[fm][r] + rb[row4*4 + (wc^1)*2 + 1];
        const float m  = st*(1.f/128.f);
        const float va = s2t*(1.f/128.f) - m*m;
        const float ri = 1.f/sqrtf(va + 1e-5f);
        const float ln = (acc2[fm][fn][r] - m)*ri*gv + bbv;
        const size_t idx = (size_t)(r0+row4)*128 + col;
        y1f[idx] = ln;
        split_store(y1ho, y1lo, idx, ln);
      }
    }
}

// ---------------- fused GAT aggregation: packed alpha, 3-deep pipeline ----------------
template<bool CONCAT>
__global__ __launch_bounds__(256) void gat_fused_kernel(const bf16* __restrict__ hfeat,
    const float* __restrict__ als, const float* __restrict__ ald,
    const int* __restrict__ offs, const unsigned short* __restrict__ csr,
    const float* __restrict__ bias, void* __restrict__ outv,
    bf16* __restrict__ qh, bf16* __restrict__ ql){
  const int w = threadIdx.x >> 6, l = threadIdx.x & 63, g = l >> 4, s16 = l & 15;
  const int nb = blockIdx.x;
  const int n = (nb & 7)*2048 + (nb >> 3)*4 + w;   // cluster-contiguous, XCD-aligned
  const float adg = ald[(size_t)n*4 + g];
  const int beg = offs[n];
  const int cnt = offs[n+1] - beg + 1;             // + implicit self-loop (edge cnt-1)
  float ev[6]; int sv[6];
#pragma unroll
  for (int p=0;p<6;p++){
    const int i = s16 + p*16;
    int src = n;
    float e = -1e30f;
    if (i < cnt){
      if (i < cnt-1) src = (int)csr[beg+i];
      float t = als[(size_t)src*4+g] + adg;
      e = fmaxf(t, 0.2f*t);                        // leaky_relu 0.2
    }
    ev[p] = e; sv[p] = src;
  }
  float m = -1e30f;
#pragma unroll
  for (int p=0;p<6;p++) m = fmaxf(m, ev[p]);
  float den = 0.f;
#pragma unroll
  for (int p=0;p<6;p++) den += (ev[p] > -1e29f) ? __expf(ev[p]-m) : 0.f;
#pragma unroll
  for (int mask=1; mask<16; mask<<=1){
    float mo = __shfl_xor(m, mask);
    float dd = __shfl_xor(den, mask);
    float nm = fmaxf(m, mo);
    den = den*__expf(m-nm) + dd*__expf(mo-nm);
    m = nm;
  }
  const float C = __expf(-m)/(den + 1e-16f);
  int pk[6];
#pragma unroll
  for (int p=0;p<6;p++){
    float a = (ev[p] > -1e29f) ? __expf(ev[p])*C : 0.f;
    bf16 ab = __float2bfloat16(a);
    pk[p] = ((int)*(unsigned short*)&ab << 16) | (sv[p] & 0xFFFF);
  }
  float acc[8] = {0,0,0,0,0,0,0,0};
  const int fb = l*8;
  const bf16* hp = hfeat + fb;
#define PROC(U,H) { const float a_ = __uint_as_float((unsigned)(U) & 0xFFFF0000u); \
  _Pragma("unroll") for (int k_=0;k_<4;k_++){ \
    acc[2*k_]   += a_ * __uint_as_float((H)[k_] << 16); \
    acc[2*k_+1] += a_ * __uint_as_float((H)[k_] & 0xFFFF0000u); } }
#pragma unroll
  for (int p=0;p<6;p++){
    const int pbase = p*16;
    if (pbase < cnt){
      const int lim = (cnt - pbase < 16) ? (cnt - pbase) : 16;
      int u0 = __shfl(pk[p], (l & 48));
      uint4v h0 = *(const uint4v*)(const void*)(hp + (size_t)(u0 & 0xFFFF)*FEAT);
      if (lim == 1){
        PROC(u0, h0);
      } else {
        int u1 = __shfl(pk[p], (l & 48) | 1);
        uint4v h1 = *(const uint4v*)(const void*)(hp + (size_t)(u1 & 0xFFFF)*FEAT);
        for (int j=2; j<lim; ++j){
          const int u2 = __shfl(pk[p], (l & 48) | j);
          const uint4v h2 = *(const uint4v*)(const void*)(hp + (size_t)(u2 & 0xFFFF)*FEAT);
          PROC(u0, h0);
          u0 = u1; h0 = h1; u1 = u2; h1 = h2;
        }
        PROC(u0, h0);
        PROC(u1, h1);
      }
    }
  }
#undef PROC
  for (int i = 96; i < cnt; ++i){
    const int src = (i < cnt-1) ? (int)csr[beg+i] : n;
    float t = als[(size_t)src*4+g] + adg;
    t = fmaxf(t, 0.2f*t);
    const float a = __expf(t)*C;
    const short8v hv = *(const short8v*)(const void*)&hfeat[(size_t)src*FEAT + fb];
#pragma unroll
    for (int k=0;k<8;k++) acc[k] += a * b2f(hv[k]);
  }
  if (CONCAT){
    short8v ov;
#pragma unroll
    for (int j=0;j<8;j++){
      float v = acc[j] + bias[fb+j];
      v = v > 0.f ? v : expm1f(v);               // fused ELU
      bf16 bv = __float2bfloat16(v);
      ov[j] = (short)*(unsigned short*)&bv;
    }
    *(short8v*)((char*)outv + ((size_t)n*FEAT + fb)*2) = ov;
  } else {
#pragma unroll
    for (int j=0;j<8;j++){
      acc[j] += __shfl_xor(acc[j], 16);
      acc[j] += __shfl_xor(acc[j], 32);
    }
    if (l < 16){
      float* op = (float*)outv + (size_t)n*128 + l*8;
#pragma unroll
      for (int j=0;j<8;j++){
        const int col = l*8 + j;
        float v = 0.25f*acc[j] + bias[col];
        float ex = __expf((float)(col & ~1) * (-9.210340371976184f/128.f));
        float pe = (col & 1) ? cosf(4.f*ex) : sinf(4.f*ex);
        float q = v + pe;
        op[j] = q;
        split_store(qh, ql, (size_t)n*128 + col, q);
      }
    }
  }
}

extern "C" void kernel_launch(void* const* d_in, const int* in_sizes, int n_in,
                              void* d_out, int out_size, void* d_ws, size_t ws_size,
                              hipStream_t stream){
  const float* x      = (const float*)d_in[0];
  const int*   ei     = (const int*)d_in[1];
  const float* W1     = (const float*)d_in[3];
  const float* a_src1 = (const float*)d_in[4];
  const float* a_dst1 = (const float*)d_in[5];
  const float* b1     = (const float*)d_in[6];
  const float* W2     = (const float*)d_in[7];
  const float* a_src2 = (const float*)d_in[8];
  const float* a_dst2 = (const float*)d_in[9];
  const float* b2     = (const float*)d_in[10];
  const float* wv     = (const float*)d_in[15];
  const float* bv     = (const float*)d_in[16];
  const float* wo     = (const float*)d_in[17];
  const float* bo     = (const float*)d_in[18];
  const float* ln_g   = (const float*)d_in[19];
  const float* ln_b   = (const float*)d_in[20];
  const float* f1     = (const float*)d_in[21];
  const float* fb1    = (const float*)d_in[22];
  const float* f2     = (const float*)d_in[23];
  const float* fb2    = (const float*)d_in[24];
  const float* wc     = (const float*)d_in[25];
  const float* bc     = (const float*)d_in[26];
  float* outp = (float*)d_out;

  const int E = in_sizes[1] / 2;
  const int n = NODES;
  const int tE = 2*E;
  const size_t MB = 1024*1024;

  const size_t NEED = 36*MB;
  if (ws_size < NEED){
    sentinel_kernel<<<(out_size+255)/256, 256, 0, stream>>>(outp, out_size,
        1000.0f + (float)(ws_size / MB));
    return;
  }

  // ---- arena [0,36) MB; liveness audited ----
  char* base = (char*)d_ws;
  int* counts = (int*)(base + 0);
  int* cursor = (int*)(base + 65536);
  bf16*  h1    = (bf16*)(base + 0);          // [0,16)  gemm1 -> agg1
  bf16*  xh    = (bf16*)(base + 16*MB);      // [16,20) prep -> gemm1
  bf16*  h     = (bf16*)(base + 16*MB);      // [16,32) agg1 -> gemm2
  bf16*  h2f   = (bf16*)(base + 0);          // [0,16)  gemm2 -> agg2
  float* h2q   = (float*)(base + 16*MB);     // [16,24) agg2 -> chain(LN1 qbuf)
  bf16*  qh    = (bf16*)(base + 24*MB);      // [24,28) agg2 -> chain
  bf16*  ql    = (bf16*)(base + 28*MB);      // [28,32)
  bf16*  y1h   = (bf16*)(base + 0);          // [0,4)   chain -> ffn1 (h2f dead)
  bf16*  y1l   = (bf16*)(base + 4*MB);       // [4,8)
  float* y1f   = (float*)(base + 8*MB);      // [8,16)  chain -> ffn2 LN2 qbuf
  bf16*  hidden= (bf16*)(base + 16*MB);      // [16,32) ffn1 -> ffn2 (h2q/qh/ql dead)
  char* u = base + 32*MB;
  bf16* w1h = (bf16*)u; u += 131072;
  bf16* w2h = (bf16*)u; u += 524288;
  bf16* wvh = (bf16*)u; u += 32768;   bf16* wvl = (bf16*)u; u += 32768;
  bf16* woh = (bf16*)u; u += 32768;   bf16* wol = (bf16*)u; u += 32768;
  bf16* f1h = (bf16*)u; u += 131072;  bf16* f1l = (bf16*)u; u += 131072;
  bf16* f2h = (bf16*)u; u += 131072;  bf16* f2l = (bf16*)u; u += 131072;
  float* als  = (float*)u; u += (size_t)n*4*4;
  float* ald  = (float*)u; u += (size_t)n*4*4;
  int* offs   = (int*)u;   u += (size_t)(n+1)*4 + 252;
  unsigned short* csr = (unsigned short*)u; u += (size_t)tE*2;

  // ---- prep + CSR ----
  PrepArgs P = { x,W1,W2,wv,wo,f1,f2, xh,w1h,w2h,wvh,wvl,woh,wol,f1h,f1l,f2h,f2l };
  prep_kernel<<<632, 256, 0, stream>>>(P);
  zero_kernel<<<(n+255)/256, 256, 0, stream>>>(counts, n);
  count_kernel<<<(tE+255)/256, 256, 0, stream>>>(ei, counts, E);
  scan_kernel<<<1, 1024, 0, stream>>>(counts, offs, cursor);
  fill_kernel<<<(tE+255)/256, 256, 0, stream>>>(ei, cursor, csr, E);

  // ---- GAT layer 1 (als/ald fused) ----
  lgemm<128,0,0,0,1,1,0><<<dim3(128,4), 256, 0, stream>>>(xh, nullptr, w1h, nullptr, nullptr,
      nullptr, h1, nullptr, 512, a_src1, a_dst1, als, ald,
      nullptr,nullptr,nullptr,nullptr,nullptr,nullptr,nullptr,nullptr,nullptr);
  gat_fused_kernel<true><<<n/4, 256, 0, stream>>>(h1, als, ald, offs, csr, b1, h, nullptr, nullptr);

  // ---- GAT layer 2 (als/ald fused) ----
  lgemm<512,0,0,0,1,1,0><<<dim3(128,4), 256, 0, stream>>>(h, nullptr, w2h, nullptr, nullptr,
      nullptr, h2f, nullptr, 512, a_src2, a_dst2, als, ald,
      nullptr,nullptr,nullptr,nullptr,nullptr,nullptr,nullptr,nullptr,nullptr);
  gat_fused_kernel<false><<<n/4, 256, 0, stream>>>(h2f, als, ald, offs, csr, b2, h2q, qh, ql);

  // ---- chained attention tail: wv+wo+LN1 in ONE kernel ----
  attn_chain_kernel<<<128, 256, 0, stream>>>(qh, ql, wvh, wvl, bv, woh, wol, bo,
      h2q, ln_g, ln_b, y1f, y1h, y1l);
  // ---- FFN ----
  lgemm<128,1,1,1,1,0,0><<<dim3(128,4), 256, 0, stream>>>(y1h, y1l, f1h, f1l, fb1,
      nullptr, hidden, nullptr, 512, nullptr, nullptr, nullptr, nullptr,
      nullptr,nullptr,nullptr,nullptr,nullptr,nullptr,nullptr,nullptr,nullptr);
  lgemm<512,0,1,0,0,0,2><<<dim3(128,1), 256, 0, stream>>>(hidden, nullptr, f2h, f2l, fb2,
      nullptr, nullptr, nullptr, 128, nullptr, nullptr, nullptr, nullptr,
      y1f, ln_g, ln_b, nullptr, nullptr, nullptr, wc, bc, outp);
}

// Round 24
// 247.149 us; speedup vs baseline: 1.2293x; 1.0118x over previous
//
#include <hip/hip_runtime.h>
#include <hip/hip_bf16.h>

#define NODES 16384
#define FEAT 512
typedef __hip_bfloat16 bf16;
typedef __hip_bfloat162 bf162;
typedef short short8v __attribute__((ext_vector_type(8)));
typedef unsigned int uint4v __attribute__((ext_vector_type(4)));
typedef float f32x4 __attribute__((ext_vector_type(4)));

static __device__ __forceinline__ float b2f(short s){
  return __uint_as_float(((unsigned)(unsigned short)s) << 16);
}
static __device__ __forceinline__ void split_store(bf16* h, bf16* l, size_t i, float v){
  bf16 hi = __float2bfloat16(v);
  h[i] = hi; l[i] = __float2bfloat16(v - __bfloat162float(hi));
}

// ---------------- diagnostic sentinel ----------------
__global__ void sentinel_kernel(float* __restrict__ out, int n, float v){
  int i = blockIdx.x*blockDim.x + threadIdx.x;
  if (i < n) out[i] = v;
}

// ---------------- CSR build ----------------
__global__ void zero_kernel(int* __restrict__ p, int n){
  int i = blockIdx.x*blockDim.x + threadIdx.x;
  if (i < n) p[i] = 0;
}
__global__ void count_kernel(const int* __restrict__ ei, int* __restrict__ counts, int E){
  int i = blockIdx.x*blockDim.x + threadIdx.x;
  if (i < 2*E){
    int dst = (i < E) ? ei[E+i] : ei[i-E];
    atomicAdd(&counts[dst], 1);
  }
}
__global__ __launch_bounds__(1024) void scan_kernel(const int* __restrict__ counts,
                                                    int* __restrict__ offs, int* __restrict__ cursor){
  __shared__ int sh[1024];
  const int t = threadIdx.x;
  int loc[16]; int s = 0;
#pragma unroll
  for (int i=0;i<16;i++){ loc[i] = counts[t*16+i]; s += loc[i]; }
  sh[t] = s; __syncthreads();
  for (int d=1; d<1024; d<<=1){
    int v = (t>=d) ? sh[t-d] : 0;
    __syncthreads(); sh[t] += v; __syncthreads();
  }
  int run = (t==0) ? 0 : sh[t-1];
#pragma unroll
  for (int i=0;i<16;i++){ offs[t*16+i] = run; cursor[t*16+i] = run; run += loc[i]; }
  if (t==1023) offs[NODES] = run;
}
__global__ void fill_kernel(const int* __restrict__ ei, int* __restrict__ cursor,
                            unsigned short* __restrict__ csr, int E){
  int i = blockIdx.x*blockDim.x + threadIdx.x;
  if (i < 2*E){
    int src = ei[i];
    int dst = (i < E) ? ei[E+i] : ei[i-E];
    int pos = atomicAdd(&cursor[dst], 1);
    csr[pos] = (unsigned short)src;
  }
}

// ---------------- prep: x cast + LDS-tiled transpose-cast of all weights ----------------
struct PrepArgs {
  const float *x,*W1,*W2,*wv,*wo,*f1,*f2;
  bf16 *xh,*w1h,*w2h,*wvh,*wvl,*woh,*wol,*f1h,*f1l,*f2h,*f2l;
};
__global__ __launch_bounds__(256) void prep_kernel(PrepArgs P){
  const int b = blockIdx.x;
  const int t = threadIdx.x;
  if (b < 512){
    const size_t base = (size_t)b*4096;
#pragma unroll
    for (int k=0;k<16;k++){
      const size_t i = base + t + 256*k;
      P.xh[i] = __float2bfloat16(P.x[i]);
    }
    return;
  }
  __shared__ float tile[64][65];
  const float* src; bf16 *dh; bf16 *dl; int R, C, ti;
  int bb = b - 512;
  if (bb < 16){ src=P.W1; dh=P.w1h; dl=nullptr; R=128; C=512; ti=bb; }
  else if ((bb-=16) < 64){ src=P.W2; dh=P.w2h; dl=nullptr; R=512; C=512; ti=bb; }
  else if ((bb-=64) < 4){ src=P.wv; dh=P.wvh; dl=P.wvl; R=128; C=128; ti=bb; }
  else if ((bb-=4) < 4){ src=P.wo; dh=P.woh; dl=P.wol; R=128; C=128; ti=bb; }
  else if ((bb-=4) < 16){ src=P.f1; dh=P.f1h; dl=P.f1l; R=128; C=512; ti=bb; }
  else { bb-=16; src=P.f2; dh=P.f2h; dl=P.f2l; R=512; C=128; ti=bb; }
  const int ctiles = C/64;
  const int r0 = (ti/ctiles)*64, c0 = (ti%ctiles)*64;
  const int r = t >> 6, c = t & 63;
#pragma unroll
  for (int i=0;i<16;i++)
    tile[r + 4*i][c] = src[(size_t)(r0 + r + 4*i)*C + c0 + c];
  __syncthreads();
#pragma unroll
  for (int i=0;i<16;i++){
    const int oc   = c0 + r + 4*i;
    const int orow = r0 + c;
    const float v = tile[c][r + 4*i];
    const size_t oi = (size_t)oc*R + orow;
    if (dl){ split_store(dh, dl, oi, v); } else { dh[oi] = __float2bfloat16(v); }
  }
}

static __device__ __forceinline__ short8v ld8(const bf16* p){
  return *(const short8v*)(const void*)(p);
}

// ---------------- LDS-staged MFMA GEMM: 128x128 tile, 4 waves ----------------
// ALS=1: fused per-(row,head) attention dots. LNM=2: fused LN + classifier head.
template<int K, int SA, int SB, int ACT, int OMODE, int ALS, int LNM>
__global__ __launch_bounds__(256) void lgemm(
    const bf16* __restrict__ A, const bf16* __restrict__ Al,
    const bf16* __restrict__ B, const bf16* __restrict__ Bl,
    const float* __restrict__ bias,
    float* __restrict__ Cf, bf16* __restrict__ Ch, bf16* __restrict__ Cl, int N,
    const float* __restrict__ as_p, const float* __restrict__ ad_p,
    float* __restrict__ als_p, float* __restrict__ ald_p,
    const float* __restrict__ qbuf, const float* __restrict__ lng, const float* __restrict__ lnb,
    float* __restrict__ y1f, bf16* __restrict__ y1ho, bf16* __restrict__ y1lo,
    const float* __restrict__ wcp, const float* __restrict__ bcp, float* __restrict__ outp){
  __shared__ bf16 As[128*40];
  __shared__ bf16 Bs[128*40];
  __shared__ bf16 Asl[SA ? 128*40 : 1];
  __shared__ bf16 Bsl[SB ? 128*40 : 1];
  const int tid = threadIdx.x;
  const int l = tid & 63, w = tid >> 6;
  const int lg = l >> 4, lr = l & 15;
  const int wr = w >> 1, wc = w & 1;
  const int r0 = blockIdx.x*128;
  const int c0 = blockIdx.y*128;
  const int srow = tid >> 1;
  const int spos = (tid & 1) * 16;
  f32x4 acc[4][4] = {};
  const int ard[4] = { (wr*64 +  0 + lr)*40 + lg*8, (wr*64 + 16 + lr)*40 + lg*8,
                       (wr*64 + 32 + lr)*40 + lg*8, (wr*64 + 48 + lr)*40 + lg*8 };
  const int brd[4] = { (wc*64 +  0 + lr)*40 + lg*8, (wc*64 + 16 + lr)*40 + lg*8,
                       (wc*64 + 32 + lr)*40 + lg*8, (wc*64 + 48 + lr)*40 + lg*8 };
  const size_t agbase = (size_t)(r0 + srow)*K + spos;
  const size_t bgbase = (size_t)(c0 + srow)*K + spos;
  const int sl = srow*40 + spos;
#pragma unroll
  for (int k0 = 0; k0 < K; k0 += 32){
    *(short8v*)&As[sl]     = ld8(A + agbase + k0);
    *(short8v*)&As[sl + 8] = ld8(A + agbase + k0 + 8);
    *(short8v*)&Bs[sl]     = ld8(B + bgbase + k0);
    *(short8v*)&Bs[sl + 8] = ld8(B + bgbase + k0 + 8);
    if (SA){
      *(short8v*)&Asl[sl]     = ld8(Al + agbase + k0);
      *(short8v*)&Asl[sl + 8] = ld8(Al + agbase + k0 + 8);
    }
    if (SB){
      *(short8v*)&Bsl[sl]     = ld8(Bl + bgbase + k0);
      *(short8v*)&Bsl[sl + 8] = ld8(Bl + bgbase + k0 + 8);
    }
    __syncthreads();
    short8v af[4], bfr[4], afl[4], bfl[4];
#pragma unroll
    for (int f=0; f<4; f++){
      af[f]  = *(const short8v*)&As[ard[f]];
      bfr[f] = *(const short8v*)&Bs[brd[f]];
      if (SA) afl[f] = *(const short8v*)&Asl[ard[f]];
      if (SB) bfl[f] = *(const short8v*)&Bsl[brd[f]];
    }
#pragma unroll
    for (int fm=0; fm<4; fm++)
#pragma unroll
      for (int fn=0; fn<4; fn++){
        acc[fm][fn] = __builtin_amdgcn_mfma_f32_16x16x32_bf16(af[fm], bfr[fn], acc[fm][fn], 0,0,0);
        if (SB) acc[fm][fn] = __builtin_amdgcn_mfma_f32_16x16x32_bf16(af[fm], bfl[fn], acc[fm][fn], 0,0,0);
        if (SA) acc[fm][fn] = __builtin_amdgcn_mfma_f32_16x16x32_bf16(afl[fm], bfr[fn], acc[fm][fn], 0,0,0);
      }
    __syncthreads();
  }
  if (LNM == 0){
    float asv[4], adv[4];
    float rs[4][4], rd[4][4];
    if (ALS){
#pragma unroll
      for (int fn=0; fn<4; fn++){
        const int col = c0 + wc*64 + fn*16 + lr;
        asv[fn] = as_p[col]; adv[fn] = ad_p[col];
      }
#pragma unroll
      for (int fm=0; fm<4; fm++)
#pragma unroll
        for (int r=0; r<4; r++){ rs[fm][r] = 0.f; rd[fm][r] = 0.f; }
    }
#pragma unroll
    for (int fm=0; fm<4; fm++){
#pragma unroll
      for (int fn=0; fn<4; fn++){
        const int col = c0 + wc*64 + fn*16 + lr;
        const float bv = bias ? bias[col] : 0.f;
#pragma unroll
        for (int r=0; r<4; r++){
          const int row = r0 + wr*64 + fm*16 + lg*4 + r;
          float v = acc[fm][fn][r] + bv;
          if (ACT==1) v = fmaxf(v, 0.f);
          const size_t idx = (size_t)row*N + col;
          if (OMODE==0) Cf[idx] = v;
          else if (OMODE==1){
            bf16 bvv = __float2bfloat16(v);
            Ch[idx] = bvv;
            if (ALS){
              const float hv = __bfloat162float(bvv);
              rs[fm][r] += hv*asv[fn];
              rd[fm][r] += hv*adv[fn];
            }
          }
          else split_store(Ch, Cl, idx, v);
        }
      }
    }
    if (ALS){
      float* rb = (float*)As;
#pragma unroll
      for (int fm=0; fm<4; fm++)
#pragma unroll
        for (int r=0; r<4; r++){
          float s = rs[fm][r], dd = rd[fm][r];
#pragma unroll
          for (int mask=1; mask<16; mask<<=1){
            s  += __shfl_xor(s,  mask);
            dd += __shfl_xor(dd, mask);
          }
          rs[fm][r] = s; rd[fm][r] = dd;
        }
      if (wc == 1 && lr == 0){
#pragma unroll
        for (int fm=0; fm<4; fm++)
#pragma unroll
          for (int r=0; r<4; r++){
            const int row = wr*64 + fm*16 + lg*4 + r;
            rb[row] = rs[fm][r]; rb[128+row] = rd[fm][r];
          }
      }
      __syncthreads();
      if (wc == 0 && lr == 0){
        const int head = blockIdx.y;
#pragma unroll
        for (int fm=0; fm<4; fm++)
#pragma unroll
          for (int r=0; r<4; r++){
            const int row = wr*64 + fm*16 + lg*4 + r;
            als_p[(size_t)(r0+row)*4 + head] = rs[fm][r] + rb[row];
            ald_p[(size_t)(r0+row)*4 + head] = rd[fm][r] + rb[128+row];
          }
      }
    }
  } else {
    // ---- fused LayerNorm + classifier head (LNM==2; N==128 full rows) ----
    float s1[4][4], s2[4][4];
#pragma unroll
    for (int fm=0; fm<4; fm++)
#pragma unroll
      for (int r=0; r<4; r++){ s1[fm][r] = 0.f; s2[fm][r] = 0.f; }
#pragma unroll
    for (int fm=0; fm<4; fm++)
#pragma unroll
      for (int fn=0; fn<4; fn++){
        const int col = wc*64 + fn*16 + lr;
        const float bv = bias[col];
#pragma unroll
        for (int r=0; r<4; r++){
          const int row = r0 + wr*64 + fm*16 + lg*4 + r;
          float xx = qbuf[(size_t)row*128 + col] + acc[fm][fn][r] + bv;
          acc[fm][fn][r] = xx;
          s1[fm][r] += xx;
          s2[fm][r] += xx*xx;
        }
      }
    float* rb = (float*)As;
#pragma unroll
    for (int fm=0; fm<4; fm++)
#pragma unroll
      for (int r=0; r<4; r++){
        float a = s1[fm][r], b = s2[fm][r];
#pragma unroll
        for (int mask=1; mask<16; mask<<=1){
          a += __shfl_xor(a, mask);
          b += __shfl_xor(b, mask);
        }
        s1[fm][r] = a; s2[fm][r] = b;
      }
    if (lr == 0){
#pragma unroll
      for (int fm=0; fm<4; fm++)
#pragma unroll
        for (int r=0; r<4; r++){
          const int row = wr*64 + fm*16 + lg*4 + r;
          rb[row*4 + wc*2 + 0] = s1[fm][r];
          rb[row*4 + wc*2 + 1] = s2[fm][r];
        }
    }
    __syncthreads();
    float mu[4][4], ri[4][4];
#pragma unroll
    for (int fm=0; fm<4; fm++)
#pragma unroll
      for (int r=0; r<4; r++){
        const int row = wr*64 + fm*16 + lg*4 + r;
        const float st  = s1[fm][r] + rb[row*4 + (wc^1)*2 + 0];
        const float s2t = s2[fm][r] + rb[row*4 + (wc^1)*2 + 1];
        const float m  = st*(1.f/128.f);
        const float va = s2t*(1.f/128.f) - m*m;
        mu[fm][r] = m;
        ri[fm][r] = 1.f/sqrtf(va + 1e-5f);
      }
    float p0[4][4], p1[4][4];
#pragma unroll
    for (int fm=0; fm<4; fm++)
#pragma unroll
      for (int r=0; r<4; r++){ p0[fm][r] = 0.f; p1[fm][r] = 0.f; }
#pragma unroll
    for (int fm=0; fm<4; fm++)
#pragma unroll
      for (int fn=0; fn<4; fn++){
        const int col = wc*64 + fn*16 + lr;
        const float gv = lng[col], bbv = lnb[col];
        const float w0 = wcp[col*2], w1 = wcp[col*2+1];
#pragma unroll
        for (int r=0; r<4; r++){
          const float ln = (acc[fm][fn][r] - mu[fm][r])*ri[fm][r]*gv + bbv;
          p0[fm][r] += ln*w0;
          p1[fm][r] += ln*w1;
        }
      }
    __syncthreads();
#pragma unroll
    for (int fm=0; fm<4; fm++)
#pragma unroll
      for (int r=0; r<4; r++){
        float a = p0[fm][r], b = p1[fm][r];
#pragma unroll
        for (int mask=1; mask<16; mask<<=1){
          a += __shfl_xor(a, mask);
          b += __shfl_xor(b, mask);
        }
        p0[fm][r] = a; p1[fm][r] = b;
      }
    if (lr == 0){
#pragma unroll
      for (int fm=0; fm<4; fm++)
#pragma unroll
        for (int r=0; r<4; r++){
          const int row = wr*64 + fm*16 + lg*4 + r;
          rb[row*4 + wc*2 + 0] = p0[fm][r];
          rb[row*4 + wc*2 + 1] = p1[fm][r];
        }
    }
    __syncthreads();
    if (wc == 0 && lr == 0){
#pragma unroll
      for (int fm=0; fm<4; fm++)
#pragma unroll
        for (int r=0; r<4; r++){
          const int row = wr*64 + fm*16 + lg*4 + r;
          outp[(size_t)(r0+row)*2 + 0] = p0[fm][r] + rb[row*4 + 2] + bcp[0];
          outp[(size_t)(r0+row)*2 + 1] = p1[fm][r] + rb[row*4 + 3] + bcp[1];
        }
    }
  }
}

// ---------------- chained attention tail: v=q@wv+bv -> ao=v@wo+bo -> LN1 ----------------
__global__ __launch_bounds__(256) void attn_chain_kernel(
    const bf16* __restrict__ qh, const bf16* __restrict__ ql,
    const bf16* __restrict__ wvh, const bf16* __restrict__ wvl,
    const float* __restrict__ bv,
    const bf16* __restrict__ woh, const bf16* __restrict__ wol,
    const float* __restrict__ bo,
    const float* __restrict__ h2q, const float* __restrict__ lng, const float* __restrict__ lnb,
    float* __restrict__ y1f, bf16* __restrict__ y1ho, bf16* __restrict__ y1lo){
  __shared__ bf16 As[128*40];
  __shared__ bf16 Bs[128*40];
  __shared__ bf16 Asl[128*40];
  __shared__ bf16 Bsl[128*40];
  const int tid = threadIdx.x;
  const int l = tid & 63, w = tid >> 6;
  const int lg = l >> 4, lr = l & 15;
  const int wr = w >> 1, wc = w & 1;
  const int r0 = blockIdx.x*128;
  const int srow = tid >> 1;
  const int spos = (tid & 1) * 16;
  const int sl = srow*40 + spos;
  const int ard[4] = { (wr*64 +  0 + lr)*40 + lg*8, (wr*64 + 16 + lr)*40 + lg*8,
                       (wr*64 + 32 + lr)*40 + lg*8, (wr*64 + 48 + lr)*40 + lg*8 };
  const int brd[4] = { (wc*64 +  0 + lr)*40 + lg*8, (wc*64 + 16 + lr)*40 + lg*8,
                       (wc*64 + 32 + lr)*40 + lg*8, (wc*64 + 48 + lr)*40 + lg*8 };
  f32x4 acc[4][4] = {};
  {
    const size_t ag = (size_t)(r0 + srow)*128 + spos;
    const size_t bg = (size_t)srow*128 + spos;
#pragma unroll
    for (int k0 = 0; k0 < 128; k0 += 32){
      *(short8v*)&As[sl]      = ld8(qh + ag + k0);
      *(short8v*)&As[sl + 8]  = ld8(qh + ag + k0 + 8);
      *(short8v*)&Asl[sl]     = ld8(ql + ag + k0);
      *(short8v*)&Asl[sl + 8] = ld8(ql + ag + k0 + 8);
      *(short8v*)&Bs[sl]      = ld8(wvh + bg + k0);
      *(short8v*)&Bs[sl + 8]  = ld8(wvh + bg + k0 + 8);
      *(short8v*)&Bsl[sl]     = ld8(wvl + bg + k0);
      *(short8v*)&Bsl[sl + 8] = ld8(wvl + bg + k0 + 8);
      __syncthreads();
      short8v af[4], bfr[4], afl[4], bfl[4];
#pragma unroll
      for (int f=0; f<4; f++){
        af[f]  = *(const short8v*)&As[ard[f]];
        bfr[f] = *(const short8v*)&Bs[brd[f]];
        afl[f] = *(const short8v*)&Asl[ard[f]];
        bfl[f] = *(const short8v*)&Bsl[brd[f]];
      }
#pragma unroll
      for (int fm=0; fm<4; fm++)
#pragma unroll
        for (int fn=0; fn<4; fn++){
          acc[fm][fn] = __builtin_amdgcn_mfma_f32_16x16x32_bf16(af[fm], bfr[fn], acc[fm][fn], 0,0,0);
          acc[fm][fn] = __builtin_amdgcn_mfma_f32_16x16x32_bf16(af[fm], bfl[fn], acc[fm][fn], 0,0,0);
          acc[fm][fn] = __builtin_amdgcn_mfma_f32_16x16x32_bf16(afl[fm], bfr[fn], acc[fm][fn], 0,0,0);
        }
      __syncthreads();
    }
  }
  f32x4 acc2[4][4] = {};
  {
    const size_t bg = (size_t)srow*128 + spos;
#pragma unroll
    for (int kb=0; kb<4; ++kb){
      if (wc == (kb >> 1)){
        const int fnb = (kb & 1)*2;
#pragma unroll
        for (int fm=0; fm<4; fm++)
#pragma unroll
          for (int fi=0; fi<2; fi++){
            const int fn = fnb + fi;
            const int col = wc*64 + fn*16 + lr;
            const float bvv = bv[col];
            const int kk = col - kb*32;
#pragma unroll
            for (int r=0; r<4; r++){
              const int row = wr*64 + fm*16 + lg*4 + r;
              const float v = acc[fm][fn][r] + bvv;
              const bf16 hi = __float2bfloat16(v);
              const bf16 lo = __float2bfloat16(v - __bfloat162float(hi));
              As[row*40 + kk]  = hi;
              Asl[row*40 + kk] = lo;
            }
          }
      }
      *(short8v*)&Bs[sl]      = ld8(woh + bg + kb*32);
      *(short8v*)&Bs[sl + 8]  = ld8(woh + bg + kb*32 + 8);
      *(short8v*)&Bsl[sl]     = ld8(wol + bg + kb*32);
      *(short8v*)&Bsl[sl + 8] = ld8(wol + bg + kb*32 + 8);
      __syncthreads();
      short8v af[4], bfr[4], afl[4], bfl[4];
#pragma unroll
      for (int f=0; f<4; f++){
        af[f]  = *(const short8v*)&As[ard[f]];
        bfr[f] = *(const short8v*)&Bs[brd[f]];
        afl[f] = *(const short8v*)&Asl[ard[f]];
        bfl[f] = *(const short8v*)&Bsl[brd[f]];
      }
#pragma unroll
      for (int fm=0; fm<4; fm++)
#pragma unroll
        for (int fn=0; fn<4; fn++){
          acc2[fm][fn] = __builtin_amdgcn_mfma_f32_16x16x32_bf16(af[fm], bfr[fn], acc2[fm][fn], 0,0,0);
          acc2[fm][fn] = __builtin_amdgcn_mfma_f32_16x16x32_bf16(af[fm], bfl[fn], acc2[fm][fn], 0,0,0);
          acc2[fm][fn] = __builtin_amdgcn_mfma_f32_16x16x32_bf16(afl[fm], bfr[fn], acc2[fm][fn], 0,0,0);
        }
      __syncthreads();
    }
  }
  float s1[4][4], s2[4][4];
#pragma unroll
  for (int fm=0; fm<4; fm++)
#pragma unroll
    for (int r=0; r<4; r++){ s1[fm][r] = 0.f; s2[fm][r] = 0.f; }
#pragma unroll
  for (int fm=0; fm<4; fm++)
#pragma unroll
    for (int fn=0; fn<4; fn++){
      const int col = wc*64 + fn*16 + lr;
      const float bvv = bo[col];
#pragma unroll
      for (int r=0; r<4; r++){
        const int row = r0 + wr*64 + fm*16 + lg*4 + r;
        float xx = h2q[(size_t)row*128 + col] + acc2[fm][fn][r] + bvv;
        acc2[fm][fn][r] = xx;
        s1[fm][r] += xx;
        s2[fm][r] += xx*xx;
      }
    }
  float* rb = (float*)As;
#pragma unroll
  for (int fm=0; fm<4; fm++)
#pragma unroll
    for (int r=0; r<4; r++){
      float a = s1[fm][r], b = s2[fm][r];
#pragma unroll
      for (int mask=1; mask<16; mask<<=1){
        a += __shfl_xor(a, mask);
        b += __shfl_xor(b, mask);
      }
      s1[fm][r] = a; s2[fm][r] = b;
    }
  if (lr == 0){
#pragma unroll
    for (int fm=0; fm<4; fm++)
#pragma unroll
      for (int r=0; r<4; r++){
        const int row = wr*64 + fm*16 + lg*4 + r;
        rb[row*4 + wc*2 + 0] = s1[fm][r];
        rb[row*4 + wc*2 + 1] = s2[fm][r];
      }
  }
  __syncthreads();
#pragma unroll
  for (int fm=0; fm<4; fm++)
#pragma unroll
    for (int fn=0; fn<4; fn++){
      const int col = wc*64 + fn*16 + lr;
      const float gv = lng[col], bbv = lnb[col];
#pragma unroll
      for (int r=0; r<4; r++){
        const int row4 = wr*64 + fm*16 + lg*4 + r;
        const float st  = s1[fm][r] + rb[row4*4 + (wc^1)*2 + 0];
        const float s2t = s2[fm][r] + rb[row4*4 + (wc^1)*2 + 1];
        const float m  = st*(1.f/128.f);
        const float va = s2t*(1.f/128.f) - m*m;
        const float ri = 1.f/sqrtf(va + 1e-5f);
        const float ln = (acc2[fm][fn][r] - m)*ri*gv + bbv;
        const size_t idx = (size_t)(r0+row4)*128 + col;
        y1f[idx] = ln;
        split_store(y1ho, y1lo, idx, ln);
      }
    }
}

// ---------------- fused GAT aggregation (r22-measured: packed alpha, 2-deep pipeline) ----------------
template<bool CONCAT>
__global__ __launch_bounds__(256) void gat_fused_kernel(const bf16* __restrict__ hfeat,
    const float* __restrict__ als, const float* __restrict__ ald,
    const int* __restrict__ offs, const unsigned short* __restrict__ csr,
    const float* __restrict__ bias, void* __restrict__ outv,
    bf16* __restrict__ qh, bf16* __restrict__ ql){
  const int w = threadIdx.x >> 6, l = threadIdx.x & 63, g = l >> 4, s16 = l & 15;
  const int nb = blockIdx.x;
  const int n = (nb & 7)*2048 + (nb >> 3)*4 + w;   // cluster-contiguous, XCD-aligned
  const float adg = ald[(size_t)n*4 + g];
  const int beg = offs[n];
  const int cnt = offs[n+1] - beg + 1;             // + implicit self-loop (edge cnt-1)
  float ev[6]; int sv[6];
#pragma unroll
  for (int p=0;p<6;p++){
    const int i = s16 + p*16;
    int src = n;
    float e = -1e30f;
    if (i < cnt){
      if (i < cnt-1) src = (int)csr[beg+i];
      float t = als[(size_t)src*4+g] + adg;
      e = fmaxf(t, 0.2f*t);                        // leaky_relu 0.2
    }
    ev[p] = e; sv[p] = src;
  }
  float m = -1e30f;
#pragma unroll
  for (int p=0;p<6;p++) m = fmaxf(m, ev[p]);
  float den = 0.f;
#pragma unroll
  for (int p=0;p<6;p++) den += (ev[p] > -1e29f) ? __expf(ev[p]-m) : 0.f;
#pragma unroll
  for (int mask=1; mask<16; mask<<=1){
    float mo = __shfl_xor(m, mask);
    float dd = __shfl_xor(den, mask);
    float nm = fmaxf(m, mo);
    den = den*__expf(m-nm) + dd*__expf(mo-nm);
    m = nm;
  }
  const float C = __expf(-m)/(den + 1e-16f);
  int pk[6];
#pragma unroll
  for (int p=0;p<6;p++){
    float a = (ev[p] > -1e29f) ? __expf(ev[p])*C : 0.f;
    bf16 ab = __float2bfloat16(a);
    pk[p] = ((int)*(unsigned short*)&ab << 16) | (sv[p] & 0xFFFF);
  }
  float acc[8] = {0,0,0,0,0,0,0,0};
  const int fb = l*8;
  const bf16* hp = hfeat + fb;
#pragma unroll
  for (int p=0;p<6;p++){
    const int pbase = p*16;
    if (pbase < cnt){
      const int lim = (cnt - pbase < 16) ? (cnt - pbase) : 16;
      int u_c = __shfl(pk[p], (l & 48));
      uint4v hv_c = *(const uint4v*)(const void*)(hp + (size_t)(u_c & 0xFFFF)*FEAT);
      for (int j=1; j<lim; ++j){
        const int u_n = __shfl(pk[p], (l & 48) | j);
        const uint4v hv_n = *(const uint4v*)(const void*)(hp + (size_t)(u_n & 0xFFFF)*FEAT);
        const float a_c = __uint_as_float((unsigned)u_c & 0xFFFF0000u);
#pragma unroll
        for (int k=0;k<4;k++){
          acc[2*k]   += a_c * __uint_as_float(hv_c[k] << 16);
          acc[2*k+1] += a_c * __uint_as_float(hv_c[k] & 0xFFFF0000u);
        }
        u_c = u_n; hv_c = hv_n;
      }
      const float a_c = __uint_as_float((unsigned)u_c & 0xFFFF0000u);
#pragma unroll
      for (int k=0;k<4;k++){
        acc[2*k]   += a_c * __uint_as_float(hv_c[k] << 16);
        acc[2*k+1] += a_c * __uint_as_float(hv_c[k] & 0xFFFF0000u);
      }
    }
  }
  for (int i = 96; i < cnt; ++i){
    const int src = (i < cnt-1) ? (int)csr[beg+i] : n;
    float t = als[(size_t)src*4+g] + adg;
    t = fmaxf(t, 0.2f*t);
    const float a = __expf(t)*C;
    const short8v hv = *(const short8v*)(const void*)&hfeat[(size_t)src*FEAT + fb];
#pragma unroll
    for (int k=0;k<8;k++) acc[k] += a * b2f(hv[k]);
  }
  if (CONCAT){
    short8v ov;
#pragma unroll
    for (int j=0;j<8;j++){
      float v = acc[j] + bias[fb+j];
      v = v > 0.f ? v : expm1f(v);               // fused ELU
      bf16 bv = __float2bfloat16(v);
      ov[j] = (short)*(unsigned short*)&bv;
    }
    *(short8v*)((char*)outv + ((size_t)n*FEAT + fb)*2) = ov;
  } else {
#pragma unroll
    for (int j=0;j<8;j++){
      acc[j] += __shfl_xor(acc[j], 16);
      acc[j] += __shfl_xor(acc[j], 32);
    }
    if (l < 16){
      float* op = (float*)outv + (size_t)n*128 + l*8;
#pragma unroll
      for (int j=0;j<8;j++){
        const int col = l*8 + j;
        float v = 0.25f*acc[j] + bias[col];
        float ex = __expf((float)(col & ~1) * (-9.210340371976184f/128.f));
        float pe = (col & 1) ? cosf(4.f*ex) : sinf(4.f*ex);
        float q = v + pe;
        op[j] = q;
        split_store(qh, ql, (size_t)n*128 + col, q);
      }
    }
  }
}

extern "C" void kernel_launch(void* const* d_in, const int* in_sizes, int n_in,
                              void* d_out, int out_size, void* d_ws, size_t ws_size,
                              hipStream_t stream){
  const float* x      = (const float*)d_in[0];
  const int*   ei     = (const int*)d_in[1];
  const float* W1     = (const float*)d_in[3];
  const float* a_src1 = (const float*)d_in[4];
  const float* a_dst1 = (const float*)d_in[5];
  const float* b1     = (const float*)d_in[6];
  const float* W2     = (const float*)d_in[7];
  const float* a_src2 = (const float*)d_in[8];
  const float* a_dst2 = (const float*)d_in[9];
  const float* b2     = (const float*)d_in[10];
  const float* wv     = (const float*)d_in[15];
  const float* bv     = (const float*)d_in[16];
  const float* wo     = (const float*)d_in[17];
  const float* bo     = (const float*)d_in[18];
  const float* ln_g   = (const float*)d_in[19];
  const float* ln_b   = (const float*)d_in[20];
  const float* f1     = (const float*)d_in[21];
  const float* fb1    = (const float*)d_in[22];
  const float* f2     = (const float*)d_in[23];
  const float* fb2    = (const float*)d_in[24];
  const float* wc     = (const float*)d_in[25];
  const float* bc     = (const float*)d_in[26];
  float* outp = (float*)d_out;

  const int E = in_sizes[1] / 2;
  const int n = NODES;
  const int tE = 2*E;
  const size_t MB = 1024*1024;

  const size_t NEED = 36*MB;
  if (ws_size < NEED){
    sentinel_kernel<<<(out_size+255)/256, 256, 0, stream>>>(outp, out_size,
        1000.0f + (float)(ws_size / MB));
    return;
  }

  // ---- arena [0,36) MB; liveness audited ----
  char* base = (char*)d_ws;
  int* counts = (int*)(base + 0);
  int* cursor = (int*)(base + 65536);
  bf16*  h1    = (bf16*)(base + 0);          // [0,16)  gemm1 -> agg1
  bf16*  xh    = (bf16*)(base + 16*MB);      // [16,20) prep -> gemm1
  bf16*  h     = (bf16*)(base + 16*MB);      // [16,32) agg1 -> gemm2
  bf16*  h2f   = (bf16*)(base + 0);          // [0,16)  gemm2 -> agg2
  float* h2q   = (float*)(base + 16*MB);     // [16,24) agg2 -> chain(LN1 qbuf)
  bf16*  qh    = (bf16*)(base + 24*MB);      // [24,28) agg2 -> chain
  bf16*  ql    = (bf16*)(base + 28*MB);      // [28,32)
  bf16*  y1h   = (bf16*)(base + 0);          // [0,4)   chain -> ffn1 (h2f dead)
  bf16*  y1l   = (bf16*)(base + 4*MB);       // [4,8)
  float* y1f   = (float*)(base + 8*MB);      // [8,16)  chain -> ffn2 LN2 qbuf
  bf16*  hidden= (bf16*)(base + 16*MB);      // [16,32) ffn1 -> ffn2 (h2q/qh/ql dead)
  char* u = base + 32*MB;
  bf16* w1h = (bf16*)u; u += 131072;
  bf16* w2h = (bf16*)u; u += 524288;
  bf16* wvh = (bf16*)u; u += 32768;   bf16* wvl = (bf16*)u; u += 32768;
  bf16* woh = (bf16*)u; u += 32768;   bf16* wol = (bf16*)u; u += 32768;
  bf16* f1h = (bf16*)u; u += 131072;  bf16* f1l = (bf16*)u; u += 131072;
  bf16* f2h = (bf16*)u; u += 131072;  bf16* f2l = (bf16*)u; u += 131072;
  float* als  = (float*)u; u += (size_t)n*4*4;
  float* ald  = (float*)u; u += (size_t)n*4*4;
  int* offs   = (int*)u;   u += (size_t)(n+1)*4 + 252;
  unsigned short* csr = (unsigned short*)u; u += (size_t)tE*2;

  // ---- prep + CSR ----
  PrepArgs P = { x,W1,W2,wv,wo,f1,f2, xh,w1h,w2h,wvh,wvl,woh,wol,f1h,f1l,f2h,f2l };
  prep_kernel<<<632, 256, 0, stream>>>(P);
  zero_kernel<<<(n+255)/256, 256, 0, stream>>>(counts, n);
  count_kernel<<<(tE+255)/256, 256, 0, stream>>>(ei, counts, E);
  scan_kernel<<<1, 1024, 0, stream>>>(counts, offs, cursor);
  fill_kernel<<<(tE+255)/256, 256, 0, stream>>>(ei, cursor, csr, E);

  // ---- GAT layer 1 (als/ald fused) ----
  lgemm<128,0,0,0,1,1,0><<<dim3(128,4), 256, 0, stream>>>(xh, nullptr, w1h, nullptr, nullptr,
      nullptr, h1, nullptr, 512, a_src1, a_dst1, als, ald,
      nullptr,nullptr,nullptr,nullptr,nullptr,nullptr,nullptr,nullptr,nullptr);
  gat_fused_kernel<true><<<n/4, 256, 0, stream>>>(h1, als, ald, offs, csr, b1, h, nullptr, nullptr);

  // ---- GAT layer 2 (als/ald fused) ----
  lgemm<512,0,0,0,1,1,0><<<dim3(128,4), 256, 0, stream>>>(h, nullptr, w2h, nullptr, nullptr,
      nullptr, h2f, nullptr, 512, a_src2, a_dst2, als, ald,
      nullptr,nullptr,nullptr,nullptr,nullptr,nullptr,nullptr,nullptr,nullptr);
  gat_fused_kernel<false><<<n/4, 256, 0, stream>>>(h2f, als, ald, offs, csr, b2, h2q, qh, ql);

  // ---- chained attention tail: wv+wo+LN1 in ONE kernel ----
  attn_chain_kernel<<<128, 256, 0, stream>>>(qh, ql, wvh, wvl, bv, woh, wol, bo,
      h2q, ln_g, ln_b, y1f, y1h, y1l);
  // ---- FFN ----
  lgemm<128,1,1,1,1,0,0><<<dim3(128,4), 256, 0, stream>>>(y1h, y1l, f1h, f1l, fb1,
      nullptr, hidden, nullptr, 512, nullptr, nullptr, nullptr, nullptr,
      nullptr,nullptr,nullptr,nullptr,nullptr,nullptr,nullptr,nullptr,nullptr);
  lgemm<512,0,1,0,0,0,2><<<dim3(128,1), 256, 0, stream>>>(hidden, nullptr, f2h, f2l, fb2,
      nullptr, nullptr, nullptr, 128, nullptr, nullptr, nullptr, nullptr,
      y1f, ln_g, ln_b, nullptr, nullptr, nullptr, wc, bc, outp);
}